// Round 10
// baseline (278.467 us; speedup 1.0000x reference)
//
#include <hip/hip_runtime.h>

#define NN 50000
#define NE 800000
#define DIM 128
#define NB 1024
#define CTXL 50
#define BN_EPS 1e-5f
#define STRIPS 3125   // NN/16
#define SCAN_B 196    // ceil(NN/256)
#define GEMM_BX 196   // gemm grid.x

// ---------------- ws layout (float offsets) ----------------
static const size_t OFF_Z    = 0;          // z fp32 [NN][128] 25.6 MB; head aliases below (z dead)
static const size_t OFF_AH   = 6400000;    // Ah bf16 [NN][128]         12.8 MB
static const size_t OFF_HBF  = 9600000;    // hbf bf16 [NN][128]        12.8 MB (fgbf then Gbf)
static const size_t OFF_EDG  = 12800000;   // (col,norm) pairs [NE][2]   6.4 MB
static const size_t OFF_RS   = 14400000;   // row_start [NN+1] int
static const size_t OFF_CUR  = 14450048;   // cursor [NN] int; ALIASED by P2 after scatter
static const size_t OFF_CNT  = 14500096;   // counts [NN] int
static const size_t OFF_SCSH = 14550400;   // scale/shift [256] f
static const size_t OFF_WH   = 14550656;   // Wh bf16 [2][128][128]
static const size_t OFF_WL   = 14567040;   // Wl bf16 [2][128][128]
static const size_t OFF_BS   = 14583424;   // bsums [256] int
static const size_t OFF_BO   = 14583680;   // boffs [256] int   (end 14583936 == r7 extent)
static const size_t OFF_P2   = OFF_CUR;    // BN partials [196][256] f
// head aliases inside dead z region: each bf16 [1024][256] = 131072 floats
static const size_t OFF_QIN  = OFF_Z;            // qin bf16
static const size_t OFF_CAT  = OFF_Z + 131072;   // cat bf16
static const size_t OFF_Q1   = OFF_Z + 262144;   // q1  bf16
static const size_t OFF_FWB  = OFF_Z + 393216;   // fusion_w bf16 [128][256] -> 16384 f
static const size_t OFF_P1B  = OFF_Z + 409600;   // proj1_w  bf16 [256][256] -> 32768 f
static const size_t OFF_P2B  = OFF_Z + 442368;   // proj2_w  bf16 [128][256] -> 16384 f (end 458752)

typedef __attribute__((ext_vector_type(8))) short s16x8;
typedef __attribute__((ext_vector_type(4))) float fx4;

__device__ __forceinline__ unsigned short f2bf(float f) {
    unsigned u = __float_as_uint(f);
    unsigned r = u + 0x7FFFu + ((u >> 16) & 1u);
    return (unsigned short)(r >> 16);
}
__device__ __forceinline__ float bf2f(unsigned short b) {
    return __uint_as_float((unsigned)b << 16);
}

// ---------------- CSR build ----------------
__global__ void hist_kernel(const int* __restrict__ row, int* __restrict__ counts) {
    int e = blockIdx.x * 256 + threadIdx.x;
    if (e < NE) atomicAdd(&counts[row[e]], 1);
}

__global__ __launch_bounds__(256) void scan_blocksums(const int* __restrict__ counts,
                                                      int* __restrict__ bsums) {
    __shared__ int red[4];
    int i = blockIdx.x * 256 + threadIdx.x;
    int v = (i < NN) ? counts[i] : 0;
    #pragma unroll
    for (int off = 32; off; off >>= 1) v += __shfl_down(v, off);
    if ((threadIdx.x & 63) == 0) red[threadIdx.x >> 6] = v;
    __syncthreads();
    if (threadIdx.x == 0) bsums[blockIdx.x] = red[0] + red[1] + red[2] + red[3];
}

__global__ __launch_bounds__(256) void scan_bsums(const int* __restrict__ bsums,
                                                  int* __restrict__ boffs) {
    __shared__ int lds[256];
    int t = threadIdx.x;
    lds[t] = (t < SCAN_B) ? bsums[t] : 0;
    __syncthreads();
    for (int off = 1; off < 256; off <<= 1) {
        int add = (t >= off) ? lds[t - off] : 0;
        __syncthreads();
        lds[t] += add;
        __syncthreads();
    }
    boffs[t] = (t == 0) ? 0 : lds[t - 1];
}

__global__ __launch_bounds__(256) void scan_final(const int* __restrict__ counts,
                                                  const int* __restrict__ boffs,
                                                  int* __restrict__ row_start,
                                                  int* __restrict__ cursor) {
    __shared__ int lds[256];
    int t = threadIdx.x;
    int i = blockIdx.x * 256 + t;
    int v = (i < NN) ? counts[i] : 0;
    lds[t] = v;
    __syncthreads();
    for (int off = 1; off < 256; off <<= 1) {
        int add = (t >= off) ? lds[t - off] : 0;
        __syncthreads();
        lds[t] += add;
        __syncthreads();
    }
    int excl = boffs[blockIdx.x] + ((t == 0) ? 0 : lds[t - 1]);
    if (i < NN) {
        row_start[i] = excl;
        cursor[i] = excl;
    }
    if (i == 0) row_start[NN] = NE;
}

// NT scattered store: random 8B writes were costing a full 64B line eviction each
// (r9: WRITE_SIZE 52MB for 6.4MB payload). Non-temporal bypasses L2 ownership.
__global__ void scatter_kernel(const int* __restrict__ row, const int* __restrict__ col,
                               const float* __restrict__ norm, int* __restrict__ cursor,
                               float* __restrict__ edge_s) {
    int e = blockIdx.x * 256 + threadIdx.x;
    if (e < NE) {
        int r = row[e];
        int p = atomicAdd(&cursor[r], 1);
        unsigned long long pk = (unsigned long long)(unsigned)col[e] |
                                ((unsigned long long)__float_as_uint(norm[e]) << 32);
        __builtin_nontemporal_store(pk, (unsigned long long*)edge_s + p);
    }
}

// ---------------- prep: W split, h cast, head-weight cast ----------------
__global__ void wsplit_kernel(const float* __restrict__ W, unsigned short* __restrict__ Wh,
                              unsigned short* __restrict__ Wl) {
    int i = blockIdx.x * 256 + threadIdx.x;
    if (i < 2 * DIM * DIM) {
        float v = W[i];
        unsigned short h = f2bf(v);
        Wh[i] = h;
        Wl[i] = f2bf(v - bf2f(h));
    }
}

__global__ void cast_bf_kernel(const float* __restrict__ in, unsigned short* __restrict__ out) {
    int i = blockIdx.x * 256 + threadIdx.x;  // float4 index
    if (i >= NN * DIM / 4) return;
    float4 v = reinterpret_cast<const float4*>(in)[i];
    ushort4 o = make_ushort4(f2bf(v.x), f2bf(v.y), f2bf(v.z), f2bf(v.w));
    reinterpret_cast<ushort4*>(out)[i] = o;
}

__global__ void headw_cast_kernel(const float* __restrict__ fw, const float* __restrict__ p1,
                                  const float* __restrict__ p2, unsigned short* __restrict__ fwb,
                                  unsigned short* __restrict__ p1b, unsigned short* __restrict__ p2b) {
    int i = blockIdx.x * 256 + threadIdx.x;
    if (i < 32768) fwb[i] = f2bf(fw[i]);
    if (i < 65536) p1b[i] = f2bf(p1[i]);
    if (i < 32768) p2b[i] = f2bf(p2[i]);
}

// ---------------- aggregation: one wave per row, gather bf16 rows, fp32 accum ----------------
__global__ __launch_bounds__(256) void agg_bf_kernel(const unsigned short* __restrict__ hbf,
                                                     const int* __restrict__ row_start,
                                                     const float* __restrict__ edge_s,
                                                     unsigned short* __restrict__ Ah) {
    int gw = (blockIdx.x * 256 + threadIdx.x) >> 6;
    int lane = threadIdx.x & 63;
    if (gw >= NN) return;
    int s = row_start[gw];
    int e = row_start[gw + 1];
    const int2* ep = (const int2*)edge_s;
    float ax = 0.f, ay = 0.f;
    int j = s;
    for (; j + 4 <= e; j += 4) {
        int2 p0 = ep[j], p1 = ep[j + 1], p2 = ep[j + 2], p3 = ep[j + 3];
        ushort2 v0 = *(const ushort2*)(hbf + (size_t)p0.x * DIM + lane * 2);
        ushort2 v1 = *(const ushort2*)(hbf + (size_t)p1.x * DIM + lane * 2);
        ushort2 v2 = *(const ushort2*)(hbf + (size_t)p2.x * DIM + lane * 2);
        ushort2 v3 = *(const ushort2*)(hbf + (size_t)p3.x * DIM + lane * 2);
        float w0 = __int_as_float(p0.y), w1 = __int_as_float(p1.y);
        float w2 = __int_as_float(p2.y), w3 = __int_as_float(p3.y);
        ax = fmaf(w0, bf2f(v0.x), ax); ay = fmaf(w0, bf2f(v0.y), ay);
        ax = fmaf(w1, bf2f(v1.x), ax); ay = fmaf(w1, bf2f(v1.y), ay);
        ax = fmaf(w2, bf2f(v2.x), ax); ay = fmaf(w2, bf2f(v2.y), ay);
        ax = fmaf(w3, bf2f(v3.x), ax); ay = fmaf(w3, bf2f(v3.y), ay);
    }
    for (; j < e; j++) {
        int2 p = ep[j];
        ushort2 v = *(const ushort2*)(hbf + (size_t)p.x * DIM + lane * 2);
        float w = __int_as_float(p.y);
        ax = fmaf(w, bf2f(v.x), ax); ay = fmaf(w, bf2f(v.y), ay);
    }
    *(ushort2*)(Ah + (size_t)gw * DIM + lane * 2) = make_ushort2(f2bf(ax), f2bf(ay));
}

// ---------------- z = relu(agg @ W^T) via MFMA, W staged in LDS, BN partials per block ----------------
__global__ __launch_bounds__(256) void gemm_mfma_kernel(const unsigned short* __restrict__ Ah,
                                                        const unsigned short* __restrict__ Wh,
                                                        const unsigned short* __restrict__ Wl,
                                                        float* __restrict__ z,
                                                        float* __restrict__ P2) {
    __shared__ __align__(16) short Wlds[2][32][128];  // 16 KB
    __shared__ float Pred[2][4][32];                  // [kind][wave][cpr]
    int tid = threadIdx.x;
    int lane = tid & 63;
    int w = tid >> 6;
    int r16 = lane & 15;
    int kg = lane >> 4;
    int cq = blockIdx.y;  // 0..3

    #pragma unroll
    for (int ff = 0; ff < 4; ff++) {
        int f = ff * 256 + tid;
        int plane = f >> 9;
        int c = (f >> 4) & 31;
        int ck = f & 15;
        const unsigned short* srcp = (plane ? Wl : Wh) + (size_t)(cq * 32 + c) * DIM + ck * 8;
        s16x8 v = *(const s16x8*)srcp;
        *(s16x8*)&Wlds[plane][c][(ck ^ (c & 7)) * 8] = v;
    }
    __syncthreads();

    int wv = (blockIdx.x * 256 + tid) >> 6;
    int nw = gridDim.x * 4;
    float bsum[2][4] = {{0.f}}, bsq[2][4] = {{0.f}};

    for (int strip = wv; strip < STRIPS; strip += nw) {
        size_t abase = (size_t)(strip * 16 + r16) * DIM + kg * 8;
        s16x8 b[4];
        #pragma unroll
        for (int ks = 0; ks < 4; ks++) b[ks] = *(const s16x8*)(Ah + abase + ks * 32);

        fx4 acc[2];
        acc[0] = (fx4){0.f, 0.f, 0.f, 0.f};
        acc[1] = (fx4){0.f, 0.f, 0.f, 0.f};
        #pragma unroll
        for (int ks = 0; ks < 4; ks++) {
            #pragma unroll
            for (int ct = 0; ct < 2; ct++) {
                int wrow = ct * 16 + r16;
                int wch = ((ks * 4 + kg) ^ (r16 & 7)) * 8;
                s16x8 wh8 = *(const s16x8*)&Wlds[0][wrow][wch];
                s16x8 wl8 = *(const s16x8*)&Wlds[1][wrow][wch];
                acc[ct] = __builtin_amdgcn_mfma_f32_16x16x32_bf16(wh8, b[ks], acc[ct], 0, 0, 0);
                acc[ct] = __builtin_amdgcn_mfma_f32_16x16x32_bf16(wl8, b[ks], acc[ct], 0, 0, 0);
            }
        }
        size_t zrow = (size_t)(strip * 16 + r16) * DIM + cq * 32 + kg * 4;
        #pragma unroll
        for (int ct = 0; ct < 2; ct++) {
            float4 o;
            o.x = fmaxf(acc[ct][0], 0.f);
            o.y = fmaxf(acc[ct][1], 0.f);
            o.z = fmaxf(acc[ct][2], 0.f);
            o.w = fmaxf(acc[ct][3], 0.f);
            bsum[ct][0] += o.x; bsq[ct][0] += o.x * o.x;
            bsum[ct][1] += o.y; bsq[ct][1] += o.y * o.y;
            bsum[ct][2] += o.z; bsq[ct][2] += o.z * o.z;
            bsum[ct][3] += o.w; bsq[ct][3] += o.w * o.w;
            *(float4*)(z + zrow + ct * 16) = o;
        }
    }

    #pragma unroll
    for (int ct = 0; ct < 2; ct++) {
        #pragma unroll
        for (int jj = 0; jj < 4; jj++) {
            float s = bsum[ct][jj], q = bsq[ct][jj];
            #pragma unroll
            for (int off = 1; off <= 8; off <<= 1) {
                s += __shfl_xor(s, off);
                q += __shfl_xor(q, off);
            }
            if (r16 == 0) {
                int cpr = ct * 16 + kg * 4 + jj;
                Pred[0][w][cpr] = s;
                Pred[1][w][cpr] = q;
            }
        }
    }
    __syncthreads();
    if (tid < 64) {
        int kind = tid >> 5, cpr = tid & 31;
        float v = (Pred[kind][0][cpr] + Pred[kind][1][cpr]) +
                  (Pred[kind][2][cpr] + Pred[kind][3][cpr]);
        P2[blockIdx.x * 256 + cq * 64 + tid] = v;
    }
}

// ---------------- BN finalize ----------------
__global__ __launch_bounds__(256) void bn_finalize_kernel(const float* __restrict__ P2,
                                                          const float* __restrict__ gamma,
                                                          const float* __restrict__ beta,
                                                          float* __restrict__ scsh) {
    __shared__ float tot[256];
    int t = threadIdx.x;
    float a0 = 0.f, a1 = 0.f, a2 = 0.f, a3 = 0.f;
    for (int bx = 0; bx < GEMM_BX; bx += 4) {
        a0 += P2[(bx + 0) * 256 + t];
        a1 += P2[(bx + 1) * 256 + t];
        a2 += P2[(bx + 2) * 256 + t];
        a3 += P2[(bx + 3) * 256 + t];
    }
    tot[t] = (a0 + a1) + (a2 + a3);
    __syncthreads();
    if (t < 128) {
        int cq = t >> 5, cp = t & 31;
        float sum = tot[cq * 64 + cp];
        float sq  = tot[cq * 64 + 32 + cp];
        float mu = sum * (1.f / (float)NN);
        float var = sq * (1.f / (float)NN) - mu * mu;
        float sc = gamma[t] / sqrtf(var + BN_EPS);
        scsh[t] = sc;
        scsh[128 + t] = beta[t] - mu * sc;
    }
}

// ---------------- h_out = h_in + z*scale + shift (+ optional bf16 emit) ----------------
__global__ __launch_bounds__(256) void residual_kernel(const float* hin,
                                                       const float* z,
                                                       const float* __restrict__ scsh,
                                                       float* hout,
                                                       unsigned short* hbf_out) {
    int i = blockIdx.x * 256 + threadIdx.x;
    if (i >= NN * DIM / 4) return;
    int c = (i * 4) & 127;
    float4 zv = reinterpret_cast<const float4*>(z)[i];
    float4 hv = reinterpret_cast<const float4*>(hin)[i];
    float4 sc = *reinterpret_cast<const float4*>(scsh + c);
    float4 sh = *reinterpret_cast<const float4*>(scsh + 128 + c);
    float4 o;
    o.x = hv.x + zv.x * sc.x + sh.x;
    o.y = hv.y + zv.y * sc.y + sh.y;
    o.z = hv.z + zv.z * sc.z + sh.z;
    o.w = hv.w + zv.w * sc.w + sh.w;
    reinterpret_cast<float4*>(hout)[i] = o;
    if (hbf_out) {
        ushort4 ob = make_ushort4(f2bf(o.x), f2bf(o.y), f2bf(o.z), f2bf(o.w));
        reinterpret_cast<ushort4*>(hbf_out)[i] = ob;
    }
}

// ---------------- pool: attention pooling + cat build (bf16 rows out) ----------------
__global__ __launch_bounds__(256) void pool_kernel(const int* __restrict__ ctx_ids,
                                                   const int* __restrict__ miss_ids,
                                                   const int* __restrict__ vocab_to_fg,
                                                   const float* __restrict__ emb_table,
                                                   const float* __restrict__ graph,
                                                   const float* __restrict__ attn_w,
                                                   const float* __restrict__ attn_b,
                                                   unsigned short* __restrict__ qinb,
                                                   unsigned short* __restrict__ catb) {
    int b = blockIdx.x;
    int tid = threadIdx.x;
    __shared__ float ctx[CTXL][129];
    __shared__ float aw[128];
    __shared__ float lg[64];

    if (tid < 128) aw[tid] = attn_w[tid];
    for (int f = tid; f < CTXL * 128; f += 256) {
        int t = f >> 7, d = f & 127;
        int vid = ctx_ids[b * CTXL + t];
        ctx[t][d] = emb_table[(size_t)vid * DIM + d];
    }
    __syncthreads();

    if (tid < CTXL) {
        float s = 0.f;
        for (int k = 0; k < 128; k++) s += ctx[tid][k] * aw[k];
        lg[tid] = s + attn_b[0];
    }
    __syncthreads();

    if (tid < 64) {
        float v = (tid < CTXL) ? lg[tid] : -INFINITY;
        float m = v;
        for (int off = 32; off; off >>= 1) m = fmaxf(m, __shfl_xor(m, off));
        float e = (tid < CTXL) ? expf(v - m) : 0.f;
        float s = e;
        for (int off = 32; off; off >>= 1) s += __shfl_xor(s, off);
        if (tid < CTXL) lg[tid] = e / s;
    }
    __syncthreads();

    int mid = miss_ids[b];
    if (tid < 128) {
        float s = 0.f;
        for (int t = 0; t < CTXL; t++) s += lg[t] * ctx[t][tid];
        qinb[(size_t)b * 256 + tid] = f2bf(s);
        catb[(size_t)b * 256 + tid] = f2bf(emb_table[(size_t)mid * DIM + tid]);
    } else {
        int d = tid - 128;
        int fg = vocab_to_fg[mid];
        float gp = (fg >= 0) ? graph[(size_t)fg * DIM + d] : 0.f;
        catb[(size_t)b * 256 + tid] = f2bf(gp);
    }
}

// ---------------- head GEMM: out[r][cgb+c] = A[r][:]@W[cgb+c][:] + bias, optional relu ----------------
__global__ __launch_bounds__(256) void head_gemm_kernel(const unsigned short* __restrict__ A,
                                                        const unsigned short* __restrict__ W,
                                                        const float* __restrict__ bias,
                                                        unsigned short* __restrict__ outb,
                                                        float* __restrict__ outf,
                                                        int ocol, int ostride, int relu) {
    __shared__ __align__(16) short Wlds[64][256];  // 32 KB
    int tid = threadIdx.x;
    int lane = tid & 63;
    int r16 = lane & 15;
    int kg = lane >> 4;
    int cgb = blockIdx.y * 64;

    #pragma unroll
    for (int ff = 0; ff < 8; ff++) {
        int f = ff * 256 + tid;
        int c = f >> 5;
        int ck = f & 31;
        s16x8 v = *(const s16x8*)(W + (size_t)(cgb + c) * 256 + ck * 8);
        *(s16x8*)&Wlds[c][(ck ^ (c & 7)) * 8] = v;
    }
    __syncthreads();

    int w = tid >> 6;
    int row = blockIdx.x * 16 + r16;

    size_t abase = (size_t)row * 256 + kg * 8;
    s16x8 bfrag[8];
    #pragma unroll
    for (int ks = 0; ks < 8; ks++) bfrag[ks] = *(const s16x8*)(A + abase + ks * 32);

    fx4 acc = (fx4){0.f, 0.f, 0.f, 0.f};
    int wrow = w * 16 + r16;
    #pragma unroll
    for (int ks = 0; ks < 8; ks++) {
        int wch = (((ks * 4 + kg) ^ (r16 & 7))) * 8;
        s16x8 w8 = *(const s16x8*)&Wlds[wrow][wch];
        acc = __builtin_amdgcn_mfma_f32_16x16x32_bf16(w8, bfrag[ks], acc, 0, 0, 0);
    }

    int cbase = cgb + w * 16 + kg * 4;
    float4 o;
    o.x = acc[0] + bias[cbase + 0];
    o.y = acc[1] + bias[cbase + 1];
    o.z = acc[2] + bias[cbase + 2];
    o.w = acc[3] + bias[cbase + 3];
    if (relu) {
        o.x = fmaxf(o.x, 0.f); o.y = fmaxf(o.y, 0.f);
        o.z = fmaxf(o.z, 0.f); o.w = fmaxf(o.w, 0.f);
    }
    size_t op = (size_t)row * ostride + ocol + cbase;
    if (outb) {
        *(ushort4*)(outb + op) = make_ushort4(f2bf(o.x), f2bf(o.y), f2bf(o.z), f2bf(o.w));
    } else {
        *(float4*)(outf + op) = o;
    }
}

extern "C" void kernel_launch(void* const* d_in, const int* in_sizes, int n_in,
                              void* d_out, int out_size, void* d_ws, size_t ws_size,
                              hipStream_t stream) {
    const int*   edge_index = (const int*)d_in[0];
    const float* norm       = (const float*)d_in[1];
    const int*   ctx_ids    = (const int*)d_in[2];
    const int*   miss_ids   = (const int*)d_in[3];
    const int*   vocab_to_fg= (const int*)d_in[4];
    const float* emb_table  = (const float*)d_in[5];
    const float* fg_emb     = (const float*)d_in[6];
    const float* gc_w       = (const float*)d_in[7];
    const float* bn_gamma   = (const float*)d_in[8];
    const float* bn_beta    = (const float*)d_in[9];
    const float* attn_w     = (const float*)d_in[10];
    const float* attn_b     = (const float*)d_in[11];
    const float* fusion_w   = (const float*)d_in[12];
    const float* fusion_b   = (const float*)d_in[13];
    const float* proj1_w    = (const float*)d_in[14];
    const float* proj1_b    = (const float*)d_in[15];
    const float* proj2_w    = (const float*)d_in[16];
    const float* proj2_b    = (const float*)d_in[17];

    const int* row = edge_index;
    const int* col = edge_index + NE;

    float* ws = (float*)d_ws;
    float*          z      = ws + OFF_Z;
    unsigned short* Ah     = (unsigned short*)(ws + OFF_AH);
    unsigned short* hbf    = (unsigned short*)(ws + OFF_HBF);
    float*          edge_s = ws + OFF_EDG;
    int*   row_start = (int*)(ws + OFF_RS);
    int*   cursor    = (int*)(ws + OFF_CUR);
    int*   counts    = (int*)(ws + OFF_CNT);
    float* scsh      = ws + OFF_SCSH;
    unsigned short* Wh = (unsigned short*)(ws + OFF_WH);
    unsigned short* Wl = (unsigned short*)(ws + OFF_WL);
    int*   bsums     = (int*)(ws + OFF_BS);
    int*   boffs     = (int*)(ws + OFF_BO);
    float* P2        = ws + OFF_P2;
    unsigned short* qinb = (unsigned short*)(ws + OFF_QIN);
    unsigned short* catb = (unsigned short*)(ws + OFF_CAT);
    unsigned short* q1b  = (unsigned short*)(ws + OFF_Q1);
    unsigned short* fwb  = (unsigned short*)(ws + OFF_FWB);
    unsigned short* p1b  = (unsigned short*)(ws + OFF_P1B);
    unsigned short* p2b  = (unsigned short*)(ws + OFF_P2B);

    float* query = (float*)d_out;
    float* G     = (float*)d_out + (size_t)NB * DIM;  // graph_embs, doubles as h

    hipMemsetAsync(counts, 0, NN * sizeof(int), stream);

    const int EB = (NE + 255) / 256;  // 3125
    wsplit_kernel<<<128, 256, 0, stream>>>(gc_w, Wh, Wl);
    cast_bf_kernel<<<6250, 256, 0, stream>>>(fg_emb, hbf);
    hist_kernel<<<EB, 256, 0, stream>>>(row, counts);
    scan_blocksums<<<SCAN_B, 256, 0, stream>>>(counts, bsums);
    scan_bsums<<<1, 256, 0, stream>>>(bsums, boffs);
    scan_final<<<SCAN_B, 256, 0, stream>>>(counts, boffs, row_start, cursor);
    scatter_kernel<<<EB, 256, 0, stream>>>(row, col, norm, cursor, edge_s);

    const int AGG_B = NN / 4;                 // 12500 blocks, one wave per row
    const int RES_B = (NN * DIM / 4) / 256;   // 6250
    dim3 gemm_grid(GEMM_BX, 4);

    // ---- layer 1 ----
    agg_bf_kernel<<<AGG_B, 256, 0, stream>>>(hbf, row_start, edge_s, Ah);
    gemm_mfma_kernel<<<gemm_grid, 256, 0, stream>>>(Ah, Wh, Wl, z, P2);
    bn_finalize_kernel<<<1, 256, 0, stream>>>(P2, bn_gamma, bn_beta, scsh);
    residual_kernel<<<RES_B, 256, 0, stream>>>(fg_emb, z, scsh, G, hbf);

    // ---- layer 2 ----
    agg_bf_kernel<<<AGG_B, 256, 0, stream>>>(hbf, row_start, edge_s, Ah);
    gemm_mfma_kernel<<<gemm_grid, 256, 0, stream>>>(Ah, Wh + DIM * DIM, Wl + DIM * DIM, z, P2);
    bn_finalize_kernel<<<1, 256, 0, stream>>>(P2, bn_gamma + 128, bn_beta + 128, scsh);
    residual_kernel<<<RES_B, 256, 0, stream>>>(G, z, scsh, G, nullptr);

    // ---- batch head: z region now dead -> head aliases live there ----
    headw_cast_kernel<<<256, 256, 0, stream>>>(fusion_w, proj1_w, proj2_w, fwb, p1b, p2b);
    pool_kernel<<<NB, 256, 0, stream>>>(ctx_ids, miss_ids, vocab_to_fg, emb_table, G,
                                        attn_w, attn_b, qinb, catb);
    dim3 hg2(64, 2), hg4(64, 4);
    head_gemm_kernel<<<hg2, 256, 0, stream>>>(catb, fwb, fusion_b, qinb, nullptr, 128, 256, 0);
    head_gemm_kernel<<<hg4, 256, 0, stream>>>(qinb, p1b, proj1_b, q1b, nullptr, 0, 256, 1);
    head_gemm_kernel<<<hg2, 256, 0, stream>>>(q1b, p2b, proj2_b, nullptr, query, 0, 128, 0);
}

// Round 11
// 217.503 us; speedup vs baseline: 1.2803x; 1.2803x over previous
//
#include <hip/hip_runtime.h>

#define NN 50000
#define NE 800000
#define DIM 128
#define NB 1024
#define CTXL 50
#define BN_EPS 1e-5f
#define STRIPS 3125   // NN/16
#define SCAN_B 196    // ceil(NN/256)
#define GEMM_BX 196   // gemm grid.x
#define NBK 49        // buckets of 1024 rows
#define BCAP 20000    // bucket capacity (mean 16384, +28 sigma)
#define ABLK 1024     // edges per passA block
#define NAB 782       // ceil(NE/ABLK)

// ---------------- ws layout (float offsets) ----------------
static const size_t OFF_Z    = 0;          // z fp32 [NN][128] 25.6MB; CSR bkt + head alias here (z dead then)
static const size_t OFF_AH   = 6400000;    // Ah bf16 [NN][128] 12.8MB; cnt/ofs/btot alias during CSR build
static const size_t OFF_HBF  = 9600000;    // hbf bf16 [NN][128]        12.8 MB (fgbf then Gbf)
static const size_t OFF_EDG  = 12800000;   // (col,norm) pairs [NE][2]   6.4 MB
static const size_t OFF_RS   = 14400000;   // row_start [NN+1] int
static const size_t OFF_CUR  = 14450048;   // cursor [NN] int (vestigial); ALIASED by P2
static const size_t OFF_CNT  = 14500096;   // counts [NN] int
static const size_t OFF_SCSH = 14550400;   // scale/shift [256] f
static const size_t OFF_WH   = 14550656;   // Wh bf16 [2][128][128]
static const size_t OFF_WL   = 14567040;   // Wl bf16 [2][128][128]
static const size_t OFF_BS   = 14583424;   // bsums [256] int
static const size_t OFF_BO   = 14583680;   // boffs [256] int   (end 14583936)
static const size_t OFF_P2   = OFF_CUR;    // BN partials [196][256] f
// CSR-build aliases (dead regions during build):
static const size_t OFF_BKT  = OFF_Z;            // bkt u64 [49][20000] = 1,960,000 floats
static const size_t OFF_ACNT = OFF_AH;           // cnt int [49][784]
static const size_t OFF_AOFS = OFF_AH + 40000;   // ofs int [49][784]
static const size_t OFF_BTOT = OFF_AH + 80000;   // btot int [49]
// head aliases inside dead z region:
static const size_t OFF_QIN  = OFF_Z;            // qin bf16 [1024][256] = 131072 f
static const size_t OFF_CAT  = OFF_Z + 131072;   // cat bf16
static const size_t OFF_Q1   = OFF_Z + 262144;   // q1  bf16
static const size_t OFF_FWB  = OFF_Z + 393216;   // fusion_w bf16
static const size_t OFF_P1B  = OFF_Z + 409600;   // proj1_w  bf16
static const size_t OFF_P2B  = OFF_Z + 442368;   // proj2_w  bf16 (end 458752)

typedef __attribute__((ext_vector_type(8))) short s16x8;
typedef __attribute__((ext_vector_type(4))) float fx4;

__device__ __forceinline__ unsigned short f2bf(float f) {
    unsigned u = __float_as_uint(f);
    unsigned r = u + 0x7FFFu + ((u >> 16) & 1u);
    return (unsigned short)(r >> 16);
}
__device__ __forceinline__ float bf2f(unsigned short b) {
    return __uint_as_float((unsigned)b << 16);
}

// ---------------- CSR build: bucketed counting sort, zero global atomics ----------------
__global__ __launch_bounds__(256) void binA_count(const int* __restrict__ row,
                                                  int* __restrict__ cnt) {
    __shared__ int c[NBK];
    int t = threadIdx.x;
    if (t < NBK) c[t] = 0;
    __syncthreads();
    int base = blockIdx.x * ABLK;
    #pragma unroll
    for (int k = 0; k < 4; k++) {
        int e = base + k * 256 + t;
        if (e < NE) atomicAdd(&c[row[e] >> 10], 1);
    }
    __syncthreads();
    if (t < NBK) cnt[t * 784 + blockIdx.x] = c[t];
}

__global__ __launch_bounds__(1024) void binA_scan(const int* __restrict__ cnt,
                                                  int* __restrict__ ofs,
                                                  int* __restrict__ btot) {
    __shared__ int lds[1024];
    int b = blockIdx.x, t = threadIdx.x;
    int v = (t < NAB) ? cnt[b * 784 + t] : 0;
    lds[t] = v;
    __syncthreads();
    for (int off = 1; off < 1024; off <<= 1) {
        int add = (t >= off) ? lds[t - off] : 0;
        __syncthreads();
        lds[t] += add;
        __syncthreads();
    }
    if (t < NAB) ofs[b * 784 + t] = lds[t] - v;   // exclusive
    if (t == NAB - 1) btot[b] = lds[t];
}

__global__ __launch_bounds__(256) void binA_scatter(const int* __restrict__ row,
                                                    const int* __restrict__ col,
                                                    const float* __restrict__ norm,
                                                    const int* __restrict__ ofs,
                                                    unsigned long long* __restrict__ bkt) {
    __shared__ int c[NBK], bofs[NBK], brsv[NBK];
    __shared__ unsigned long long stage[ABLK];
    __shared__ unsigned char stgb[ABLK];
    int t = threadIdx.x;
    if (t < NBK) c[t] = 0;
    __syncthreads();
    int base = blockIdx.x * ABLK;
    int my_b[4], my_i[4];
    unsigned long long my_pk[4];
    #pragma unroll
    for (int k = 0; k < 4; k++) {
        int e = base + k * 256 + t;
        if (e < NE) {
            int r = row[e];
            int b = r >> 10;
            my_b[k] = b;
            my_i[k] = atomicAdd(&c[b], 1);
            my_pk[k] = ((unsigned long long)__float_as_uint(norm[e]) << 32)
                     | ((unsigned long long)(unsigned)col[e] << 10)
                     | (unsigned)(r & 1023);
        } else my_b[k] = -1;
    }
    __syncthreads();
    if (t == 0) {
        int s = 0;
        for (int b = 0; b < NBK; b++) { bofs[b] = s; s += c[b]; }
    }
    if (t < NBK) brsv[t] = ofs[t * 784 + blockIdx.x];
    __syncthreads();
    #pragma unroll
    for (int k = 0; k < 4; k++) {
        if (my_b[k] >= 0) {
            int j = bofs[my_b[k]] + my_i[k];
            stage[j] = my_pk[k];
            stgb[j] = (unsigned char)my_b[k];
        }
    }
    __syncthreads();
    int tot = min(NE - base, ABLK);
    for (int j = t; j < tot; j += 256) {
        int b = stgb[j];
        int dst = brsv[b] + (j - bofs[b]);
        if (dst < BCAP) bkt[(size_t)b * BCAP + dst] = stage[j];
    }
}

// per-bucket row histogram -> counts[] (replaces hist + memset; zero global atomics)
__global__ __launch_bounds__(1024) void binB_count(const unsigned long long* __restrict__ bkt,
                                                   const int* __restrict__ btot,
                                                   int* __restrict__ counts) {
    __shared__ int c[1024];
    int b = blockIdx.x, t = threadIdx.x;
    c[t] = 0;
    __syncthreads();
    int n = btot[b];
    for (int i = t; i < n; i += 1024) {
        int lr = (int)(bkt[(size_t)b * BCAP + i] & 1023u);
        atomicAdd(&c[lr], 1);
    }
    __syncthreads();
    int r = (b << 10) + t;
    if (r < NN) counts[r] = c[t];
}

// final scatter: one block per bucket -> single-CU-owned 135KB CSR segment (L2 assembles lines)
__global__ __launch_bounds__(1024) void binB_scatter(const unsigned long long* __restrict__ bkt,
                                                     const int* __restrict__ btot,
                                                     const int* __restrict__ row_start,
                                                     unsigned long long* __restrict__ edge_out) {
    __shared__ int cur[1024];
    int b = blockIdx.x, t = threadIdx.x;
    cur[t] = 0;
    __syncthreads();
    int n = btot[b];
    int rbase = b << 10;
    for (int i = t; i < n; i += 1024) {
        unsigned long long pk = bkt[(size_t)b * BCAP + i];
        int lr = (int)(pk & 1023u);
        unsigned colv = (unsigned)((pk >> 10) & 0xFFFFu);
        unsigned nrm = (unsigned)(pk >> 32);
        int k = atomicAdd(&cur[lr], 1);
        int pos = row_start[rbase + lr] + k;
        edge_out[pos] = ((unsigned long long)nrm << 32) | colv;
    }
}

// ---- 3-phase scan over counts (unchanged) ----
__global__ __launch_bounds__(256) void scan_blocksums(const int* __restrict__ counts,
                                                      int* __restrict__ bsums) {
    __shared__ int red[4];
    int i = blockIdx.x * 256 + threadIdx.x;
    int v = (i < NN) ? counts[i] : 0;
    #pragma unroll
    for (int off = 32; off; off >>= 1) v += __shfl_down(v, off);
    if ((threadIdx.x & 63) == 0) red[threadIdx.x >> 6] = v;
    __syncthreads();
    if (threadIdx.x == 0) bsums[blockIdx.x] = red[0] + red[1] + red[2] + red[3];
}

__global__ __launch_bounds__(256) void scan_bsums(const int* __restrict__ bsums,
                                                  int* __restrict__ boffs) {
    __shared__ int lds[256];
    int t = threadIdx.x;
    lds[t] = (t < SCAN_B) ? bsums[t] : 0;
    __syncthreads();
    for (int off = 1; off < 256; off <<= 1) {
        int add = (t >= off) ? lds[t - off] : 0;
        __syncthreads();
        lds[t] += add;
        __syncthreads();
    }
    boffs[t] = (t == 0) ? 0 : lds[t - 1];
}

__global__ __launch_bounds__(256) void scan_final(const int* __restrict__ counts,
                                                  const int* __restrict__ boffs,
                                                  int* __restrict__ row_start) {
    __shared__ int lds[256];
    int t = threadIdx.x;
    int i = blockIdx.x * 256 + t;
    int v = (i < NN) ? counts[i] : 0;
    lds[t] = v;
    __syncthreads();
    for (int off = 1; off < 256; off <<= 1) {
        int add = (t >= off) ? lds[t - off] : 0;
        __syncthreads();
        lds[t] += add;
        __syncthreads();
    }
    int excl = boffs[blockIdx.x] + ((t == 0) ? 0 : lds[t - 1]);
    if (i < NN) row_start[i] = excl;
    if (i == 0) row_start[NN] = NE;
}

// ---------------- prep: W split, h cast, head-weight cast ----------------
__global__ void wsplit_kernel(const float* __restrict__ W, unsigned short* __restrict__ Wh,
                              unsigned short* __restrict__ Wl) {
    int i = blockIdx.x * 256 + threadIdx.x;
    if (i < 2 * DIM * DIM) {
        float v = W[i];
        unsigned short h = f2bf(v);
        Wh[i] = h;
        Wl[i] = f2bf(v - bf2f(h));
    }
}

__global__ void cast_bf_kernel(const float* __restrict__ in, unsigned short* __restrict__ out) {
    int i = blockIdx.x * 256 + threadIdx.x;  // float4 index
    if (i >= NN * DIM / 4) return;
    float4 v = reinterpret_cast<const float4*>(in)[i];
    ushort4 o = make_ushort4(f2bf(v.x), f2bf(v.y), f2bf(v.z), f2bf(v.w));
    reinterpret_cast<ushort4*>(out)[i] = o;
}

__global__ void headw_cast_kernel(const float* __restrict__ fw, const float* __restrict__ p1,
                                  const float* __restrict__ p2, unsigned short* __restrict__ fwb,
                                  unsigned short* __restrict__ p1b, unsigned short* __restrict__ p2b) {
    int i = blockIdx.x * 256 + threadIdx.x;
    if (i < 32768) fwb[i] = f2bf(fw[i]);
    if (i < 65536) p1b[i] = f2bf(p1[i]);
    if (i < 32768) p2b[i] = f2bf(p2[i]);
}

// ---------------- aggregation: one wave per row, gather bf16 rows, fp32 accum ----------------
__global__ __launch_bounds__(256) void agg_bf_kernel(const unsigned short* __restrict__ hbf,
                                                     const int* __restrict__ row_start,
                                                     const float* __restrict__ edge_s,
                                                     unsigned short* __restrict__ Ah) {
    int gw = (blockIdx.x * 256 + threadIdx.x) >> 6;
    int lane = threadIdx.x & 63;
    if (gw >= NN) return;
    int s = row_start[gw];
    int e = row_start[gw + 1];
    const int2* ep = (const int2*)edge_s;
    float ax = 0.f, ay = 0.f;
    int j = s;
    for (; j + 4 <= e; j += 4) {
        int2 p0 = ep[j], p1 = ep[j + 1], p2 = ep[j + 2], p3 = ep[j + 3];
        ushort2 v0 = *(const ushort2*)(hbf + (size_t)p0.x * DIM + lane * 2);
        ushort2 v1 = *(const ushort2*)(hbf + (size_t)p1.x * DIM + lane * 2);
        ushort2 v2 = *(const ushort2*)(hbf + (size_t)p2.x * DIM + lane * 2);
        ushort2 v3 = *(const ushort2*)(hbf + (size_t)p3.x * DIM + lane * 2);
        float w0 = __int_as_float(p0.y), w1 = __int_as_float(p1.y);
        float w2 = __int_as_float(p2.y), w3 = __int_as_float(p3.y);
        ax = fmaf(w0, bf2f(v0.x), ax); ay = fmaf(w0, bf2f(v0.y), ay);
        ax = fmaf(w1, bf2f(v1.x), ax); ay = fmaf(w1, bf2f(v1.y), ay);
        ax = fmaf(w2, bf2f(v2.x), ax); ay = fmaf(w2, bf2f(v2.y), ay);
        ax = fmaf(w3, bf2f(v3.x), ax); ay = fmaf(w3, bf2f(v3.y), ay);
    }
    for (; j < e; j++) {
        int2 p = ep[j];
        ushort2 v = *(const ushort2*)(hbf + (size_t)p.x * DIM + lane * 2);
        float w = __int_as_float(p.y);
        ax = fmaf(w, bf2f(v.x), ax); ay = fmaf(w, bf2f(v.y), ay);
    }
    *(ushort2*)(Ah + (size_t)gw * DIM + lane * 2) = make_ushort2(f2bf(ax), f2bf(ay));
}

// ---------------- z = relu(agg @ W^T) via MFMA, W staged in LDS, BN partials per block ----------------
__global__ __launch_bounds__(256) void gemm_mfma_kernel(const unsigned short* __restrict__ Ah,
                                                        const unsigned short* __restrict__ Wh,
                                                        const unsigned short* __restrict__ Wl,
                                                        float* __restrict__ z,
                                                        float* __restrict__ P2) {
    __shared__ __align__(16) short Wlds[2][32][128];  // 16 KB
    __shared__ float Pred[2][4][32];
    int tid = threadIdx.x;
    int lane = tid & 63;
    int w = tid >> 6;
    int r16 = lane & 15;
    int kg = lane >> 4;
    int cq = blockIdx.y;

    #pragma unroll
    for (int ff = 0; ff < 4; ff++) {
        int f = ff * 256 + tid;
        int plane = f >> 9;
        int c = (f >> 4) & 31;
        int ck = f & 15;
        const unsigned short* srcp = (plane ? Wl : Wh) + (size_t)(cq * 32 + c) * DIM + ck * 8;
        s16x8 v = *(const s16x8*)srcp;
        *(s16x8*)&Wlds[plane][c][(ck ^ (c & 7)) * 8] = v;
    }
    __syncthreads();

    int wv = (blockIdx.x * 256 + tid) >> 6;
    int nw = gridDim.x * 4;
    float bsum[2][4] = {{0.f}}, bsq[2][4] = {{0.f}};

    for (int strip = wv; strip < STRIPS; strip += nw) {
        size_t abase = (size_t)(strip * 16 + r16) * DIM + kg * 8;
        s16x8 b[4];
        #pragma unroll
        for (int ks = 0; ks < 4; ks++) b[ks] = *(const s16x8*)(Ah + abase + ks * 32);

        fx4 acc[2];
        acc[0] = (fx4){0.f, 0.f, 0.f, 0.f};
        acc[1] = (fx4){0.f, 0.f, 0.f, 0.f};
        #pragma unroll
        for (int ks = 0; ks < 4; ks++) {
            #pragma unroll
            for (int ct = 0; ct < 2; ct++) {
                int wrow = ct * 16 + r16;
                int wch = ((ks * 4 + kg) ^ (r16 & 7)) * 8;
                s16x8 wh8 = *(const s16x8*)&Wlds[0][wrow][wch];
                s16x8 wl8 = *(const s16x8*)&Wlds[1][wrow][wch];
                acc[ct] = __builtin_amdgcn_mfma_f32_16x16x32_bf16(wh8, b[ks], acc[ct], 0, 0, 0);
                acc[ct] = __builtin_amdgcn_mfma_f32_16x16x32_bf16(wl8, b[ks], acc[ct], 0, 0, 0);
            }
        }
        size_t zrow = (size_t)(strip * 16 + r16) * DIM + cq * 32 + kg * 4;
        #pragma unroll
        for (int ct = 0; ct < 2; ct++) {
            float4 o;
            o.x = fmaxf(acc[ct][0], 0.f);
            o.y = fmaxf(acc[ct][1], 0.f);
            o.z = fmaxf(acc[ct][2], 0.f);
            o.w = fmaxf(acc[ct][3], 0.f);
            bsum[ct][0] += o.x; bsq[ct][0] += o.x * o.x;
            bsum[ct][1] += o.y; bsq[ct][1] += o.y * o.y;
            bsum[ct][2] += o.z; bsq[ct][2] += o.z * o.z;
            bsum[ct][3] += o.w; bsq[ct][3] += o.w * o.w;
            *(float4*)(z + zrow + ct * 16) = o;
        }
    }

    #pragma unroll
    for (int ct = 0; ct < 2; ct++) {
        #pragma unroll
        for (int jj = 0; jj < 4; jj++) {
            float s = bsum[ct][jj], q = bsq[ct][jj];
            #pragma unroll
            for (int off = 1; off <= 8; off <<= 1) {
                s += __shfl_xor(s, off);
                q += __shfl_xor(q, off);
            }
            if (r16 == 0) {
                int cpr = ct * 16 + kg * 4 + jj;
                Pred[0][w][cpr] = s;
                Pred[1][w][cpr] = q;
            }
        }
    }
    __syncthreads();
    if (tid < 64) {
        int kind = tid >> 5, cpr = tid & 31;
        float v = (Pred[kind][0][cpr] + Pred[kind][1][cpr]) +
                  (Pred[kind][2][cpr] + Pred[kind][3][cpr]);
        P2[blockIdx.x * 256 + cq * 64 + tid] = v;
    }
}

// ---------------- BN finalize ----------------
__global__ __launch_bounds__(256) void bn_finalize_kernel(const float* __restrict__ P2,
                                                          const float* __restrict__ gamma,
                                                          const float* __restrict__ beta,
                                                          float* __restrict__ scsh) {
    __shared__ float tot[256];
    int t = threadIdx.x;
    float a0 = 0.f, a1 = 0.f, a2 = 0.f, a3 = 0.f;
    for (int bx = 0; bx < GEMM_BX; bx += 4) {
        a0 += P2[(bx + 0) * 256 + t];
        a1 += P2[(bx + 1) * 256 + t];
        a2 += P2[(bx + 2) * 256 + t];
        a3 += P2[(bx + 3) * 256 + t];
    }
    tot[t] = (a0 + a1) + (a2 + a3);
    __syncthreads();
    if (t < 128) {
        int cq = t >> 5, cp = t & 31;
        float sum = tot[cq * 64 + cp];
        float sq  = tot[cq * 64 + 32 + cp];
        float mu = sum * (1.f / (float)NN);
        float var = sq * (1.f / (float)NN) - mu * mu;
        float sc = gamma[t] / sqrtf(var + BN_EPS);
        scsh[t] = sc;
        scsh[128 + t] = beta[t] - mu * sc;
    }
}

// ---------------- h_out = h_in + z*scale + shift (+ optional bf16 emit) ----------------
__global__ __launch_bounds__(256) void residual_kernel(const float* hin,
                                                       const float* z,
                                                       const float* __restrict__ scsh,
                                                       float* hout,
                                                       unsigned short* hbf_out) {
    int i = blockIdx.x * 256 + threadIdx.x;
    if (i >= NN * DIM / 4) return;
    int c = (i * 4) & 127;
    float4 zv = reinterpret_cast<const float4*>(z)[i];
    float4 hv = reinterpret_cast<const float4*>(hin)[i];
    float4 sc = *reinterpret_cast<const float4*>(scsh + c);
    float4 sh = *reinterpret_cast<const float4*>(scsh + 128 + c);
    float4 o;
    o.x = hv.x + zv.x * sc.x + sh.x;
    o.y = hv.y + zv.y * sc.y + sh.y;
    o.z = hv.z + zv.z * sc.z + sh.z;
    o.w = hv.w + zv.w * sc.w + sh.w;
    reinterpret_cast<float4*>(hout)[i] = o;
    if (hbf_out) {
        ushort4 ob = make_ushort4(f2bf(o.x), f2bf(o.y), f2bf(o.z), f2bf(o.w));
        reinterpret_cast<ushort4*>(hbf_out)[i] = ob;
    }
}

// ---------------- pool: attention pooling + cat build (bf16 rows out) ----------------
__global__ __launch_bounds__(256) void pool_kernel(const int* __restrict__ ctx_ids,
                                                   const int* __restrict__ miss_ids,
                                                   const int* __restrict__ vocab_to_fg,
                                                   const float* __restrict__ emb_table,
                                                   const float* __restrict__ graph,
                                                   const float* __restrict__ attn_w,
                                                   const float* __restrict__ attn_b,
                                                   unsigned short* __restrict__ qinb,
                                                   unsigned short* __restrict__ catb) {
    int b = blockIdx.x;
    int tid = threadIdx.x;
    __shared__ float ctx[CTXL][129];
    __shared__ float aw[128];
    __shared__ float lg[64];

    if (tid < 128) aw[tid] = attn_w[tid];
    for (int f = tid; f < CTXL * 128; f += 256) {
        int t = f >> 7, d = f & 127;
        int vid = ctx_ids[b * CTXL + t];
        ctx[t][d] = emb_table[(size_t)vid * DIM + d];
    }
    __syncthreads();

    if (tid < CTXL) {
        float s = 0.f;
        for (int k = 0; k < 128; k++) s += ctx[tid][k] * aw[k];
        lg[tid] = s + attn_b[0];
    }
    __syncthreads();

    if (tid < 64) {
        float v = (tid < CTXL) ? lg[tid] : -INFINITY;
        float m = v;
        for (int off = 32; off; off >>= 1) m = fmaxf(m, __shfl_xor(m, off));
        float e = (tid < CTXL) ? expf(v - m) : 0.f;
        float s = e;
        for (int off = 32; off; off >>= 1) s += __shfl_xor(s, off);
        if (tid < CTXL) lg[tid] = e / s;
    }
    __syncthreads();

    int mid = miss_ids[b];
    if (tid < 128) {
        float s = 0.f;
        for (int t = 0; t < CTXL; t++) s += lg[t] * ctx[t][tid];
        qinb[(size_t)b * 256 + tid] = f2bf(s);
        catb[(size_t)b * 256 + tid] = f2bf(emb_table[(size_t)mid * DIM + tid]);
    } else {
        int d = tid - 128;
        int fg = vocab_to_fg[mid];
        float gp = (fg >= 0) ? graph[(size_t)fg * DIM + d] : 0.f;
        catb[(size_t)b * 256 + tid] = f2bf(gp);
    }
}

// ---------------- head GEMM ----------------
__global__ __launch_bounds__(256) void head_gemm_kernel(const unsigned short* __restrict__ A,
                                                        const unsigned short* __restrict__ W,
                                                        const float* __restrict__ bias,
                                                        unsigned short* __restrict__ outb,
                                                        float* __restrict__ outf,
                                                        int ocol, int ostride, int relu) {
    __shared__ __align__(16) short Wlds[64][256];  // 32 KB
    int tid = threadIdx.x;
    int lane = tid & 63;
    int r16 = lane & 15;
    int kg = lane >> 4;
    int cgb = blockIdx.y * 64;

    #pragma unroll
    for (int ff = 0; ff < 8; ff++) {
        int f = ff * 256 + tid;
        int c = f >> 5;
        int ck = f & 31;
        s16x8 v = *(const s16x8*)(W + (size_t)(cgb + c) * 256 + ck * 8);
        *(s16x8*)&Wlds[c][(ck ^ (c & 7)) * 8] = v;
    }
    __syncthreads();

    int w = tid >> 6;
    int row = blockIdx.x * 16 + r16;

    size_t abase = (size_t)row * 256 + kg * 8;
    s16x8 bfrag[8];
    #pragma unroll
    for (int ks = 0; ks < 8; ks++) bfrag[ks] = *(const s16x8*)(A + abase + ks * 32);

    fx4 acc = (fx4){0.f, 0.f, 0.f, 0.f};
    int wrow = w * 16 + r16;
    #pragma unroll
    for (int ks = 0; ks < 8; ks++) {
        int wch = (((ks * 4 + kg) ^ (r16 & 7))) * 8;
        s16x8 w8 = *(const s16x8*)&Wlds[wrow][wch];
        acc = __builtin_amdgcn_mfma_f32_16x16x32_bf16(w8, bfrag[ks], acc, 0, 0, 0);
    }

    int cbase = cgb + w * 16 + kg * 4;
    float4 o;
    o.x = acc[0] + bias[cbase + 0];
    o.y = acc[1] + bias[cbase + 1];
    o.z = acc[2] + bias[cbase + 2];
    o.w = acc[3] + bias[cbase + 3];
    if (relu) {
        o.x = fmaxf(o.x, 0.f); o.y = fmaxf(o.y, 0.f);
        o.z = fmaxf(o.z, 0.f); o.w = fmaxf(o.w, 0.f);
    }
    size_t op = (size_t)row * ostride + ocol + cbase;
    if (outb) {
        *(ushort4*)(outb + op) = make_ushort4(f2bf(o.x), f2bf(o.y), f2bf(o.z), f2bf(o.w));
    } else {
        *(float4*)(outf + op) = o;
    }
}

extern "C" void kernel_launch(void* const* d_in, const int* in_sizes, int n_in,
                              void* d_out, int out_size, void* d_ws, size_t ws_size,
                              hipStream_t stream) {
    const int*   edge_index = (const int*)d_in[0];
    const float* norm       = (const float*)d_in[1];
    const int*   ctx_ids    = (const int*)d_in[2];
    const int*   miss_ids   = (const int*)d_in[3];
    const int*   vocab_to_fg= (const int*)d_in[4];
    const float* emb_table  = (const float*)d_in[5];
    const float* fg_emb     = (const float*)d_in[6];
    const float* gc_w       = (const float*)d_in[7];
    const float* bn_gamma   = (const float*)d_in[8];
    const float* bn_beta    = (const float*)d_in[9];
    const float* attn_w     = (const float*)d_in[10];
    const float* attn_b     = (const float*)d_in[11];
    const float* fusion_w   = (const float*)d_in[12];
    const float* fusion_b   = (const float*)d_in[13];
    const float* proj1_w    = (const float*)d_in[14];
    const float* proj1_b    = (const float*)d_in[15];
    const float* proj2_w    = (const float*)d_in[16];
    const float* proj2_b    = (const float*)d_in[17];

    const int* row = edge_index;
    const int* col = edge_index + NE;

    float* ws = (float*)d_ws;
    float*          z      = ws + OFF_Z;
    unsigned short* Ah     = (unsigned short*)(ws + OFF_AH);
    unsigned short* hbf    = (unsigned short*)(ws + OFF_HBF);
    float*          edge_s = ws + OFF_EDG;
    int*   row_start = (int*)(ws + OFF_RS);
    int*   counts    = (int*)(ws + OFF_CNT);
    float* scsh      = ws + OFF_SCSH;
    unsigned short* Wh = (unsigned short*)(ws + OFF_WH);
    unsigned short* Wl = (unsigned short*)(ws + OFF_WL);
    int*   bsums     = (int*)(ws + OFF_BS);
    int*   boffs     = (int*)(ws + OFF_BO);
    float* P2        = ws + OFF_P2;
    unsigned long long* bkt = (unsigned long long*)(ws + OFF_BKT);
    int*   acnt      = (int*)(ws + OFF_ACNT);
    int*   aofs      = (int*)(ws + OFF_AOFS);
    int*   btot      = (int*)(ws + OFF_BTOT);
    unsigned short* qinb = (unsigned short*)(ws + OFF_QIN);
    unsigned short* catb = (unsigned short*)(ws + OFF_CAT);
    unsigned short* q1b  = (unsigned short*)(ws + OFF_Q1);
    unsigned short* fwb  = (unsigned short*)(ws + OFF_FWB);
    unsigned short* p1b  = (unsigned short*)(ws + OFF_P1B);
    unsigned short* p2b  = (unsigned short*)(ws + OFF_P2B);

    float* query = (float*)d_out;
    float* G     = (float*)d_out + (size_t)NB * DIM;  // graph_embs, doubles as h

    // ---- CSR build (bucketed counting sort, zero global atomics) ----
    binA_count<<<NAB, 256, 0, stream>>>(row, acnt);
    binA_scan<<<NBK, 1024, 0, stream>>>(acnt, aofs, btot);
    binA_scatter<<<NAB, 256, 0, stream>>>(row, col, norm, aofs, bkt);
    binB_count<<<NBK, 1024, 0, stream>>>(bkt, btot, counts);
    scan_blocksums<<<SCAN_B, 256, 0, stream>>>(counts, bsums);
    scan_bsums<<<1, 256, 0, stream>>>(bsums, boffs);
    scan_final<<<SCAN_B, 256, 0, stream>>>(counts, boffs, row_start);
    binB_scatter<<<NBK, 1024, 0, stream>>>(bkt, btot, row_start, (unsigned long long*)edge_s);

    // ---- prep ----
    wsplit_kernel<<<128, 256, 0, stream>>>(gc_w, Wh, Wl);
    cast_bf_kernel<<<6250, 256, 0, stream>>>(fg_emb, hbf);

    const int AGG_B = NN / 4;                 // 12500 blocks, one wave per row
    const int RES_B = (NN * DIM / 4) / 256;   // 6250
    dim3 gemm_grid(GEMM_BX, 4);

    // ---- layer 1 ----
    agg_bf_kernel<<<AGG_B, 256, 0, stream>>>(hbf, row_start, edge_s, Ah);
    gemm_mfma_kernel<<<gemm_grid, 256, 0, stream>>>(Ah, Wh, Wl, z, P2);
    bn_finalize_kernel<<<1, 256, 0, stream>>>(P2, bn_gamma, bn_beta, scsh);
    residual_kernel<<<RES_B, 256, 0, stream>>>(fg_emb, z, scsh, G, hbf);

    // ---- layer 2 ----
    agg_bf_kernel<<<AGG_B, 256, 0, stream>>>(hbf, row_start, edge_s, Ah);
    gemm_mfma_kernel<<<gemm_grid, 256, 0, stream>>>(Ah, Wh + DIM * DIM, Wl + DIM * DIM, z, P2);
    bn_finalize_kernel<<<1, 256, 0, stream>>>(P2, bn_gamma + 128, bn_beta + 128, scsh);
    residual_kernel<<<RES_B, 256, 0, stream>>>(G, z, scsh, G, nullptr);

    // ---- batch head: z region now dead -> head aliases live there ----
    headw_cast_kernel<<<256, 256, 0, stream>>>(fusion_w, proj1_w, proj2_w, fwb, p1b, p2b);
    pool_kernel<<<NB, 256, 0, stream>>>(ctx_ids, miss_ids, vocab_to_fg, emb_table, G,
                                        attn_w, attn_b, qinb, catb);
    dim3 hg2(64, 2), hg4(64, 4);
    head_gemm_kernel<<<hg2, 256, 0, stream>>>(catb, fwb, fusion_b, qinb, nullptr, 128, 256, 0);
    head_gemm_kernel<<<hg4, 256, 0, stream>>>(qinb, p1b, proj1_b, q1b, nullptr, 0, 256, 1);
    head_gemm_kernel<<<hg2, 256, 0, stream>>>(q1b, p2b, proj2_b, nullptr, query, 0, 128, 0);
}

// Round 12
// 201.055 us; speedup vs baseline: 1.3850x; 1.0818x over previous
//
#include <hip/hip_runtime.h>

#define NN 50000
#define NE 800000
#define DIM 128
#define NB 1024
#define CTXL 50
#define BN_EPS 1e-5f
#define STRIPS 3125   // NN/16
#define GEMM_BX 196   // gemm grid.x
#define NBK 49        // buckets of 1024 rows
#define BCAP 20000    // bucket capacity
#define ABLK 1024     // edges per passA block
#define NAB 782       // ceil(NE/ABLK)

// ---------------- ws layout (float offsets) ----------------
static const size_t OFF_Z    = 0;          // zb bf16 [NN][128] 12.8MB; CSR bkt + head alias here too
static const size_t OFF_AH   = 6400000;    // Ah bf16 [NN][128] 12.8MB; cnt/ofs/btot alias during CSR build
static const size_t OFF_HBF  = 9600000;    // hbf bf16 [NN][128] 12.8 MB (fgbf then Gbf)
static const size_t OFF_EDG  = 12800000;   // (col,norm) pairs [NE][2] 6.4 MB
static const size_t OFF_RS   = 14400000;   // row_start [NN+1] int
static const size_t OFF_CUR  = 14450048;   // (vestigial) ALIASED by P2
static const size_t OFF_CNT  = 14500096;   // (vestigial)
static const size_t OFF_SCSH = 14550400;   // scale/shift [256] f
static const size_t OFF_WH   = 14550656;   // Wh bf16 [2][128][128]
static const size_t OFF_WL   = 14567040;   // Wl bf16 [2][128][128]
static const size_t OFF_P2   = OFF_CUR;    // BN partials [196][256] f
// CSR-build aliases (dead regions during build):
static const size_t OFF_BKT  = OFF_Z + 3200000;  // bkt u64 [49][20000] = 1.96M floats (clear of zb)
static const size_t OFF_ACNT = OFF_AH;           // cnt int [49][784]
static const size_t OFF_AOFS = OFF_AH + 40000;   // ofs int [49][784]
static const size_t OFF_BTOT = OFF_AH + 80000;   // btot int [49]
// head aliases inside dead zb region (after residual2):
static const size_t OFF_QIN  = OFF_Z;            // qin bf16 [1024][256] = 131072 f
static const size_t OFF_CAT  = OFF_Z + 131072;   // cat bf16
static const size_t OFF_Q1   = OFF_Z + 262144;   // q1  bf16
static const size_t OFF_FWB  = OFF_Z + 393216;   // fusion_w bf16
static const size_t OFF_P1B  = OFF_Z + 409600;   // proj1_w  bf16
static const size_t OFF_P2B  = OFF_Z + 442368;   // proj2_w  bf16 (end 458752)

typedef __attribute__((ext_vector_type(8))) short s16x8;
typedef __attribute__((ext_vector_type(4))) float fx4;

__device__ __forceinline__ unsigned short f2bf(float f) {
    unsigned u = __float_as_uint(f);
    unsigned r = u + 0x7FFFu + ((u >> 16) & 1u);
    return (unsigned short)(r >> 16);
}
__device__ __forceinline__ float bf2f(unsigned short b) {
    return __uint_as_float((unsigned)b << 16);
}

// ---------------- CSR build: bucketed counting sort, zero global atomics ----------------
__global__ __launch_bounds__(256) void binA_count(const int* __restrict__ row,
                                                  int* __restrict__ cnt) {
    __shared__ int c[NBK];
    int t = threadIdx.x;
    if (t < NBK) c[t] = 0;
    __syncthreads();
    int base = blockIdx.x * ABLK;
    #pragma unroll
    for (int k = 0; k < 4; k++) {
        int e = base + k * 256 + t;
        if (e < NE) atomicAdd(&c[row[e] >> 10], 1);
    }
    __syncthreads();
    if (t < NBK) cnt[t * 784 + blockIdx.x] = c[t];
}

__global__ __launch_bounds__(1024) void binA_scan(const int* __restrict__ cnt,
                                                  int* __restrict__ ofs,
                                                  int* __restrict__ btot) {
    __shared__ int lds[1024];
    int b = blockIdx.x, t = threadIdx.x;
    int v = (t < NAB) ? cnt[b * 784 + t] : 0;
    lds[t] = v;
    __syncthreads();
    for (int off = 1; off < 1024; off <<= 1) {
        int add = (t >= off) ? lds[t - off] : 0;
        __syncthreads();
        lds[t] += add;
        __syncthreads();
    }
    if (t < NAB) ofs[b * 784 + t] = lds[t] - v;   // exclusive
    if (t == NAB - 1) btot[b] = lds[t];
}

__global__ __launch_bounds__(256) void binA_scatter(const int* __restrict__ row,
                                                    const int* __restrict__ col,
                                                    const float* __restrict__ norm,
                                                    const int* __restrict__ ofs,
                                                    unsigned long long* __restrict__ bkt) {
    __shared__ int c[NBK], bofs[NBK], brsv[NBK];
    __shared__ unsigned long long stage[ABLK];
    __shared__ unsigned char stgb[ABLK];
    int t = threadIdx.x;
    if (t < NBK) c[t] = 0;
    __syncthreads();
    int base = blockIdx.x * ABLK;
    int my_b[4], my_i[4];
    unsigned long long my_pk[4];
    #pragma unroll
    for (int k = 0; k < 4; k++) {
        int e = base + k * 256 + t;
        if (e < NE) {
            int r = row[e];
            int b = r >> 10;
            my_b[k] = b;
            my_i[k] = atomicAdd(&c[b], 1);
            my_pk[k] = ((unsigned long long)__float_as_uint(norm[e]) << 32)
                     | ((unsigned long long)(unsigned)col[e] << 10)
                     | (unsigned)(r & 1023);
        } else my_b[k] = -1;
    }
    __syncthreads();
    if (t == 0) {
        int s = 0;
        for (int b = 0; b < NBK; b++) { bofs[b] = s; s += c[b]; }
    }
    if (t < NBK) brsv[t] = ofs[t * 784 + blockIdx.x];
    __syncthreads();
    #pragma unroll
    for (int k = 0; k < 4; k++) {
        if (my_b[k] >= 0) {
            int j = bofs[my_b[k]] + my_i[k];
            stage[j] = my_pk[k];
            stgb[j] = (unsigned char)my_b[k];
        }
    }
    __syncthreads();
    int tot = min(NE - base, ABLK);
    for (int j = t; j < tot; j += 256) {
        int b = stgb[j];
        int dst = brsv[b] + (j - bofs[b]);
        if (dst < BCAP) bkt[(size_t)b * BCAP + dst] = stage[j];
    }
}

// per-bucket histogram + in-block prefix -> row_start directly (replaces count + 3 scan kernels)
__global__ __launch_bounds__(1024) void binB_rowstart(const unsigned long long* __restrict__ bkt,
                                                      const int* __restrict__ btot,
                                                      int* __restrict__ row_start) {
    __shared__ int c[1024];
    __shared__ int gofs_s;
    int b = blockIdx.x, t = threadIdx.x;
    c[t] = 0;
    if (t < 64) {
        int v = (t < b) ? btot[t] : 0;
        #pragma unroll
        for (int off = 32; off; off >>= 1) v += __shfl_down(v, off);
        if (t == 0) gofs_s = v;
    }
    __syncthreads();
    int n = btot[b];
    for (int i = t; i < n; i += 1024) {
        atomicAdd(&c[(int)(bkt[(size_t)b * BCAP + i] & 1023u)], 1);
    }
    __syncthreads();
    int myc = c[t];
    for (int off = 1; off < 1024; off <<= 1) {
        int add = (t >= off) ? c[t - off] : 0;
        __syncthreads();
        c[t] += add;
        __syncthreads();
    }
    int excl = gofs_s + c[t] - myc;
    int r = (b << 10) + t;
    if (r <= NN) row_start[r] = excl;   // r==NN lands here naturally with excl==NE
}

// final scatter: one block per bucket -> single-CU-owned CSR segment
__global__ __launch_bounds__(1024) void binB_scatter(const unsigned long long* __restrict__ bkt,
                                                     const int* __restrict__ btot,
                                                     const int* __restrict__ row_start,
                                                     unsigned long long* __restrict__ edge_out) {
    __shared__ int cur[1024];
    int b = blockIdx.x, t = threadIdx.x;
    cur[t] = 0;
    __syncthreads();
    int n = btot[b];
    int rbase = b << 10;
    for (int i = t; i < n; i += 1024) {
        unsigned long long pk = bkt[(size_t)b * BCAP + i];
        int lr = (int)(pk & 1023u);
        unsigned colv = (unsigned)((pk >> 10) & 0xFFFFu);
        unsigned nrm = (unsigned)(pk >> 32);
        int k = atomicAdd(&cur[lr], 1);
        int pos = row_start[rbase + lr] + k;
        edge_out[pos] = ((unsigned long long)nrm << 32) | colv;
    }
}

// ---------------- prep: W split + h cast (fused) ----------------
__global__ void prep_kernel(const float* __restrict__ W, const float* __restrict__ fg,
                            unsigned short* __restrict__ Wh, unsigned short* __restrict__ Wl,
                            unsigned short* __restrict__ hbf) {
    int i = blockIdx.x * 256 + threadIdx.x;
    if (i < 2 * DIM * DIM) {
        float v = W[i];
        unsigned short h = f2bf(v);
        Wh[i] = h;
        Wl[i] = f2bf(v - bf2f(h));
    }
    if (i < NN * DIM / 4) {
        float4 v = reinterpret_cast<const float4*>(fg)[i];
        reinterpret_cast<ushort4*>(hbf)[i] =
            make_ushort4(f2bf(v.x), f2bf(v.y), f2bf(v.z), f2bf(v.w));
    }
}

// ---------------- aggregation: one wave per row, half-wave edge split, ushort4 loads ----------------
__global__ __launch_bounds__(256) void agg_bf_kernel(const unsigned short* __restrict__ hbf,
                                                     const int* __restrict__ row_start,
                                                     const float* __restrict__ edge_s,
                                                     unsigned short* __restrict__ Ah) {
    int gw = (blockIdx.x * 256 + threadIdx.x) >> 6;
    int lane = threadIdx.x & 63;
    int half = lane >> 5;
    int c4 = (lane & 31) * 4;   // 4 channels per lane
    if (gw >= NN) return;
    int s = row_start[gw];
    int e = row_start[gw + 1];
    const int2* ep = (const int2*)edge_s;
    float a0 = 0.f, a1 = 0.f, a2 = 0.f, a3 = 0.f;
    int j = s + half;
    for (; j + 6 < e; j += 8) {  // 4 edges per half per iter (stride 2)
        int2 p0 = ep[j], p1 = ep[j + 2], p2 = ep[j + 4], p3 = ep[j + 6];
        ushort4 v0 = *(const ushort4*)(hbf + (size_t)p0.x * DIM + c4);
        ushort4 v1 = *(const ushort4*)(hbf + (size_t)p1.x * DIM + c4);
        ushort4 v2 = *(const ushort4*)(hbf + (size_t)p2.x * DIM + c4);
        ushort4 v3 = *(const ushort4*)(hbf + (size_t)p3.x * DIM + c4);
        float w0 = __int_as_float(p0.y), w1 = __int_as_float(p1.y);
        float w2 = __int_as_float(p2.y), w3 = __int_as_float(p3.y);
        a0 = fmaf(w0, bf2f(v0.x), a0); a1 = fmaf(w0, bf2f(v0.y), a1);
        a2 = fmaf(w0, bf2f(v0.z), a2); a3 = fmaf(w0, bf2f(v0.w), a3);
        a0 = fmaf(w1, bf2f(v1.x), a0); a1 = fmaf(w1, bf2f(v1.y), a1);
        a2 = fmaf(w1, bf2f(v1.z), a2); a3 = fmaf(w1, bf2f(v1.w), a3);
        a0 = fmaf(w2, bf2f(v2.x), a0); a1 = fmaf(w2, bf2f(v2.y), a1);
        a2 = fmaf(w2, bf2f(v2.z), a2); a3 = fmaf(w2, bf2f(v2.w), a3);
        a0 = fmaf(w3, bf2f(v3.x), a0); a1 = fmaf(w3, bf2f(v3.y), a1);
        a2 = fmaf(w3, bf2f(v3.z), a2); a3 = fmaf(w3, bf2f(v3.w), a3);
    }
    for (; j < e; j += 2) {
        int2 p = ep[j];
        ushort4 v = *(const ushort4*)(hbf + (size_t)p.x * DIM + c4);
        float w = __int_as_float(p.y);
        a0 = fmaf(w, bf2f(v.x), a0); a1 = fmaf(w, bf2f(v.y), a1);
        a2 = fmaf(w, bf2f(v.z), a2); a3 = fmaf(w, bf2f(v.w), a3);
    }
    a0 += __shfl_xor(a0, 32); a1 += __shfl_xor(a1, 32);
    a2 += __shfl_xor(a2, 32); a3 += __shfl_xor(a3, 32);
    if (half == 0) {
        *(ushort4*)(Ah + (size_t)gw * DIM + c4) =
            make_ushort4(f2bf(a0), f2bf(a1), f2bf(a2), f2bf(a3));
    }
}

// ---------------- z = relu(agg @ W^T) via MFMA, W staged in LDS, bf16 z out ----------------
__global__ __launch_bounds__(256) void gemm_mfma_kernel(const unsigned short* __restrict__ Ah,
                                                        const unsigned short* __restrict__ Wh,
                                                        const unsigned short* __restrict__ Wl,
                                                        unsigned short* __restrict__ zb,
                                                        float* __restrict__ P2) {
    __shared__ __align__(16) short Wlds[2][32][128];  // 16 KB
    __shared__ float Pred[2][4][32];
    int tid = threadIdx.x;
    int lane = tid & 63;
    int w = tid >> 6;
    int r16 = lane & 15;
    int kg = lane >> 4;
    int cq = blockIdx.y;

    #pragma unroll
    for (int ff = 0; ff < 4; ff++) {
        int f = ff * 256 + tid;
        int plane = f >> 9;
        int c = (f >> 4) & 31;
        int ck = f & 15;
        const unsigned short* srcp = (plane ? Wl : Wh) + (size_t)(cq * 32 + c) * DIM + ck * 8;
        s16x8 v = *(const s16x8*)srcp;
        *(s16x8*)&Wlds[plane][c][(ck ^ (c & 7)) * 8] = v;
    }
    __syncthreads();

    int wv = (blockIdx.x * 256 + tid) >> 6;
    int nw = gridDim.x * 4;
    float bsum[2][4] = {{0.f}}, bsq[2][4] = {{0.f}};

    for (int strip = wv; strip < STRIPS; strip += nw) {
        size_t abase = (size_t)(strip * 16 + r16) * DIM + kg * 8;
        s16x8 b[4];
        #pragma unroll
        for (int ks = 0; ks < 4; ks++) b[ks] = *(const s16x8*)(Ah + abase + ks * 32);

        fx4 acc[2];
        acc[0] = (fx4){0.f, 0.f, 0.f, 0.f};
        acc[1] = (fx4){0.f, 0.f, 0.f, 0.f};
        #pragma unroll
        for (int ks = 0; ks < 4; ks++) {
            #pragma unroll
            for (int ct = 0; ct < 2; ct++) {
                int wrow = ct * 16 + r16;
                int wch = ((ks * 4 + kg) ^ (r16 & 7)) * 8;
                s16x8 wh8 = *(const s16x8*)&Wlds[0][wrow][wch];
                s16x8 wl8 = *(const s16x8*)&Wlds[1][wrow][wch];
                acc[ct] = __builtin_amdgcn_mfma_f32_16x16x32_bf16(wh8, b[ks], acc[ct], 0, 0, 0);
                acc[ct] = __builtin_amdgcn_mfma_f32_16x16x32_bf16(wl8, b[ks], acc[ct], 0, 0, 0);
            }
        }
        size_t zrow = (size_t)(strip * 16 + r16) * DIM + cq * 32 + kg * 4;
        #pragma unroll
        for (int ct = 0; ct < 2; ct++) {
            float x0 = fmaxf(acc[ct][0], 0.f);
            float x1 = fmaxf(acc[ct][1], 0.f);
            float x2 = fmaxf(acc[ct][2], 0.f);
            float x3 = fmaxf(acc[ct][3], 0.f);
            bsum[ct][0] += x0; bsq[ct][0] += x0 * x0;
            bsum[ct][1] += x1; bsq[ct][1] += x1 * x1;
            bsum[ct][2] += x2; bsq[ct][2] += x2 * x2;
            bsum[ct][3] += x3; bsq[ct][3] += x3 * x3;
            *(ushort4*)(zb + zrow + ct * 16) = make_ushort4(f2bf(x0), f2bf(x1), f2bf(x2), f2bf(x3));
        }
    }

    #pragma unroll
    for (int ct = 0; ct < 2; ct++) {
        #pragma unroll
        for (int jj = 0; jj < 4; jj++) {
            float s = bsum[ct][jj], q = bsq[ct][jj];
            #pragma unroll
            for (int off = 1; off <= 8; off <<= 1) {
                s += __shfl_xor(s, off);
                q += __shfl_xor(q, off);
            }
            if (r16 == 0) {
                int cpr = ct * 16 + kg * 4 + jj;
                Pred[0][w][cpr] = s;
                Pred[1][w][cpr] = q;
            }
        }
    }
    __syncthreads();
    if (tid < 64) {
        int kind = tid >> 5, cpr = tid & 31;
        float v = (Pred[kind][0][cpr] + Pred[kind][1][cpr]) +
                  (Pred[kind][2][cpr] + Pred[kind][3][cpr]);
        P2[blockIdx.x * 256 + cq * 64 + tid] = v;
    }
}

// ---------------- BN finalize ----------------
__global__ __launch_bounds__(256) void bn_finalize_kernel(const float* __restrict__ P2,
                                                          const float* __restrict__ gamma,
                                                          const float* __restrict__ beta,
                                                          float* __restrict__ scsh) {
    __shared__ float tot[256];
    int t = threadIdx.x;
    float a0 = 0.f, a1 = 0.f, a2 = 0.f, a3 = 0.f;
    for (int bx = 0; bx < GEMM_BX; bx += 4) {
        a0 += P2[(bx + 0) * 256 + t];
        a1 += P2[(bx + 1) * 256 + t];
        a2 += P2[(bx + 2) * 256 + t];
        a3 += P2[(bx + 3) * 256 + t];
    }
    tot[t] = (a0 + a1) + (a2 + a3);
    __syncthreads();
    if (t < 128) {
        int cq = t >> 5, cp = t & 31;
        float sum = tot[cq * 64 + cp];
        float sq  = tot[cq * 64 + 32 + cp];
        float mu = sum * (1.f / (float)NN);
        float var = sq * (1.f / (float)NN) - mu * mu;
        float sc = gamma[t] / sqrtf(var + BN_EPS);
        scsh[t] = sc;
        scsh[128 + t] = beta[t] - mu * sc;
    }
}

// ---------------- h_out = h_in + zb*scale + shift (+ optional bf16 emit) ----------------
__global__ __launch_bounds__(256) void residual_kernel(const float* hin,
                                                       const unsigned short* zb,
                                                       const float* __restrict__ scsh,
                                                       float* hout,
                                                       unsigned short* hbf_out) {
    int i = blockIdx.x * 256 + threadIdx.x;
    if (i >= NN * DIM / 4) return;
    int c = (i * 4) & 127;
    ushort4 z4 = reinterpret_cast<const ushort4*>(zb)[i];
    float4 hv = reinterpret_cast<const float4*>(hin)[i];
    float4 sc = *reinterpret_cast<const float4*>(scsh + c);
    float4 sh = *reinterpret_cast<const float4*>(scsh + 128 + c);
    float4 o;
    o.x = hv.x + bf2f(z4.x) * sc.x + sh.x;
    o.y = hv.y + bf2f(z4.y) * sc.y + sh.y;
    o.z = hv.z + bf2f(z4.z) * sc.z + sh.z;
    o.w = hv.w + bf2f(z4.w) * sc.w + sh.w;
    reinterpret_cast<float4*>(hout)[i] = o;
    if (hbf_out) {
        ushort4 ob = make_ushort4(f2bf(o.x), f2bf(o.y), f2bf(o.z), f2bf(o.w));
        reinterpret_cast<ushort4*>(hbf_out)[i] = ob;
    }
}

// ---------------- pool: attention pooling + cat build + distributed head-weight cast ----------------
__global__ __launch_bounds__(256) void pool_kernel(const int* __restrict__ ctx_ids,
                                                   const int* __restrict__ miss_ids,
                                                   const int* __restrict__ vocab_to_fg,
                                                   const float* __restrict__ emb_table,
                                                   const float* __restrict__ graph,
                                                   const float* __restrict__ attn_w,
                                                   const float* __restrict__ attn_b,
                                                   const float* __restrict__ fusion_w,
                                                   const float* __restrict__ proj1_w,
                                                   const float* __restrict__ proj2_w,
                                                   unsigned short* __restrict__ qinb,
                                                   unsigned short* __restrict__ catb,
                                                   unsigned short* __restrict__ fwb,
                                                   unsigned short* __restrict__ p1b,
                                                   unsigned short* __restrict__ p2b) {
    int b = blockIdx.x;
    int tid = threadIdx.x;
    __shared__ float ctx[CTXL][129];
    __shared__ float aw[128];
    __shared__ float lg[64];

    // distributed head-weight cast: 1024 blocks x 128 elems = 131072 total
    if (tid < 128) {
        int i = b * 128 + tid;
        if (i < 32768) fwb[i] = f2bf(fusion_w[i]);
        else if (i < 98304) p1b[i - 32768] = f2bf(proj1_w[i - 32768]);
        else p2b[i - 98304] = f2bf(proj2_w[i - 98304]);
    }

    if (tid < 128) aw[tid] = attn_w[tid];
    // ctx staging: float4 gathers (50 rows x 32 float4)
    for (int f = tid; f < CTXL * 32; f += 256) {
        int t = f >> 5, d4 = (f & 31) * 4;
        int vid = ctx_ids[b * CTXL + t];
        float4 v = *(const float4*)(emb_table + (size_t)vid * DIM + d4);
        ctx[t][d4 + 0] = v.x; ctx[t][d4 + 1] = v.y;
        ctx[t][d4 + 2] = v.z; ctx[t][d4 + 3] = v.w;
    }
    __syncthreads();

    if (tid < CTXL) {
        float s = 0.f;
        for (int k = 0; k < 128; k++) s += ctx[tid][k] * aw[k];
        lg[tid] = s + attn_b[0];
    }
    __syncthreads();

    if (tid < 64) {
        float v = (tid < CTXL) ? lg[tid] : -INFINITY;
        float m = v;
        for (int off = 32; off; off >>= 1) m = fmaxf(m, __shfl_xor(m, off));
        float e = (tid < CTXL) ? expf(v - m) : 0.f;
        float s = e;
        for (int off = 32; off; off >>= 1) s += __shfl_xor(s, off);
        if (tid < CTXL) lg[tid] = e / s;
    }
    __syncthreads();

    int mid = miss_ids[b];
    if (tid < 128) {
        float s = 0.f;
        for (int t = 0; t < CTXL; t++) s += lg[t] * ctx[t][tid];
        qinb[(size_t)b * 256 + tid] = f2bf(s);
        catb[(size_t)b * 256 + tid] = f2bf(emb_table[(size_t)mid * DIM + tid]);
    } else {
        int d = tid - 128;
        int fg = vocab_to_fg[mid];
        float gp = (fg >= 0) ? graph[(size_t)fg * DIM + d] : 0.f;
        catb[(size_t)b * 256 + tid] = f2bf(gp);
    }
}

// ---------------- head GEMM ----------------
__global__ __launch_bounds__(256) void head_gemm_kernel(const unsigned short* __restrict__ A,
                                                        const unsigned short* __restrict__ W,
                                                        const float* __restrict__ bias,
                                                        unsigned short* __restrict__ outb,
                                                        float* __restrict__ outf,
                                                        int ocol, int ostride, int relu) {
    __shared__ __align__(16) short Wlds[64][256];  // 32 KB
    int tid = threadIdx.x;
    int lane = tid & 63;
    int r16 = lane & 15;
    int kg = lane >> 4;
    int cgb = blockIdx.y * 64;

    #pragma unroll
    for (int ff = 0; ff < 8; ff++) {
        int f = ff * 256 + tid;
        int c = f >> 5;
        int ck = f & 31;
        s16x8 v = *(const s16x8*)(W + (size_t)(cgb + c) * 256 + ck * 8);
        *(s16x8*)&Wlds[c][(ck ^ (c & 7)) * 8] = v;
    }
    __syncthreads();

    int w = tid >> 6;
    int row = blockIdx.x * 16 + r16;

    size_t abase = (size_t)row * 256 + kg * 8;
    s16x8 bfrag[8];
    #pragma unroll
    for (int ks = 0; ks < 8; ks++) bfrag[ks] = *(const s16x8*)(A + abase + ks * 32);

    fx4 acc = (fx4){0.f, 0.f, 0.f, 0.f};
    int wrow = w * 16 + r16;
    #pragma unroll
    for (int ks = 0; ks < 8; ks++) {
        int wch = (((ks * 4 + kg) ^ (r16 & 7))) * 8;
        s16x8 w8 = *(const s16x8*)&Wlds[wrow][wch];
        acc = __builtin_amdgcn_mfma_f32_16x16x32_bf16(w8, bfrag[ks], acc, 0, 0, 0);
    }

    int cbase = cgb + w * 16 + kg * 4;
    float4 o;
    o.x = acc[0] + bias[cbase + 0];
    o.y = acc[1] + bias[cbase + 1];
    o.z = acc[2] + bias[cbase + 2];
    o.w = acc[3] + bias[cbase + 3];
    if (relu) {
        o.x = fmaxf(o.x, 0.f); o.y = fmaxf(o.y, 0.f);
        o.z = fmaxf(o.z, 0.f); o.w = fmaxf(o.w, 0.f);
    }
    size_t op = (size_t)row * ostride + ocol + cbase;
    if (outb) {
        *(ushort4*)(outb + op) = make_ushort4(f2bf(o.x), f2bf(o.y), f2bf(o.z), f2bf(o.w));
    } else {
        *(float4*)(outf + op) = o;
    }
}

extern "C" void kernel_launch(void* const* d_in, const int* in_sizes, int n_in,
                              void* d_out, int out_size, void* d_ws, size_t ws_size,
                              hipStream_t stream) {
    const int*   edge_index = (const int*)d_in[0];
    const float* norm       = (const float*)d_in[1];
    const int*   ctx_ids    = (const int*)d_in[2];
    const int*   miss_ids   = (const int*)d_in[3];
    const int*   vocab_to_fg= (const int*)d_in[4];
    const float* emb_table  = (const float*)d_in[5];
    const float* fg_emb     = (const float*)d_in[6];
    const float* gc_w       = (const float*)d_in[7];
    const float* bn_gamma   = (const float*)d_in[8];
    const float* bn_beta    = (const float*)d_in[9];
    const float* attn_w     = (const float*)d_in[10];
    const float* attn_b     = (const float*)d_in[11];
    const float* fusion_w   = (const float*)d_in[12];
    const float* fusion_b   = (const float*)d_in[13];
    const float* proj1_w    = (const float*)d_in[14];
    const float* proj1_b    = (const float*)d_in[15];
    const float* proj2_w    = (const float*)d_in[16];
    const float* proj2_b    = (const float*)d_in[17];

    const int* row = edge_index;
    const int* col = edge_index + NE;

    float* ws = (float*)d_ws;
    unsigned short* zb     = (unsigned short*)(ws + OFF_Z);
    unsigned short* Ah     = (unsigned short*)(ws + OFF_AH);
    unsigned short* hbf    = (unsigned short*)(ws + OFF_HBF);
    float*          edge_s = ws + OFF_EDG;
    int*   row_start = (int*)(ws + OFF_RS);
    float* scsh      = ws + OFF_SCSH;
    unsigned short* Wh = (unsigned short*)(ws + OFF_WH);
    unsigned short* Wl = (unsigned short*)(ws + OFF_WL);
    float* P2        = ws + OFF_P2;
    unsigned long long* bkt = (unsigned long long*)(ws + OFF_BKT);
    int*   acnt      = (int*)(ws + OFF_ACNT);
    int*   aofs      = (int*)(ws + OFF_AOFS);
    int*   btot      = (int*)(ws + OFF_BTOT);
    unsigned short* qinb = (unsigned short*)(ws + OFF_QIN);
    unsigned short* catb = (unsigned short*)(ws + OFF_CAT);
    unsigned short* q1b  = (unsigned short*)(ws + OFF_Q1);
    unsigned short* fwb  = (unsigned short*)(ws + OFF_FWB);
    unsigned short* p1b  = (unsigned short*)(ws + OFF_P1B);
    unsigned short* p2b  = (unsigned short*)(ws + OFF_P2B);

    float* query = (float*)d_out;
    float* G     = (float*)d_out + (size_t)NB * DIM;  // graph_embs, doubles as h

    // ---- CSR build (bucketed counting sort, zero global atomics) ----
    binA_count<<<NAB, 256, 0, stream>>>(row, acnt);
    binA_scan<<<NBK, 1024, 0, stream>>>(acnt, aofs, btot);
    binA_scatter<<<NAB, 256, 0, stream>>>(row, col, norm, aofs, bkt);
    binB_rowstart<<<NBK, 1024, 0, stream>>>(bkt, btot, row_start);
    binB_scatter<<<NBK, 1024, 0, stream>>>(bkt, btot, row_start, (unsigned long long*)edge_s);

    // ---- prep (W split + h cast fused) ----
    prep_kernel<<<6250, 256, 0, stream>>>(gc_w, fg_emb, Wh, Wl, hbf);

    const int AGG_B = NN / 4;                 // 12500 blocks, one wave per row
    const int RES_B = (NN * DIM / 4) / 256;   // 6250
    dim3 gemm_grid(GEMM_BX, 4);

    // ---- layer 1 ----
    agg_bf_kernel<<<AGG_B, 256, 0, stream>>>(hbf, row_start, edge_s, Ah);
    gemm_mfma_kernel<<<gemm_grid, 256, 0, stream>>>(Ah, Wh, Wl, zb, P2);
    bn_finalize_kernel<<<1, 256, 0, stream>>>(P2, bn_gamma, bn_beta, scsh);
    residual_kernel<<<RES_B, 256, 0, stream>>>(fg_emb, zb, scsh, G, hbf);

    // ---- layer 2 ----
    agg_bf_kernel<<<AGG_B, 256, 0, stream>>>(hbf, row_start, edge_s, Ah);
    gemm_mfma_kernel<<<gemm_grid, 256, 0, stream>>>(Ah, Wh + DIM * DIM, Wl + DIM * DIM, zb, P2);
    bn_finalize_kernel<<<1, 256, 0, stream>>>(P2, bn_gamma + 128, bn_beta + 128, scsh);
    residual_kernel<<<RES_B, 256, 0, stream>>>(G, zb, scsh, G, nullptr);

    // ---- batch head: zb region now dead -> head aliases live there ----
    pool_kernel<<<NB, 256, 0, stream>>>(ctx_ids, miss_ids, vocab_to_fg, emb_table, G,
                                        attn_w, attn_b, fusion_w, proj1_w, proj2_w,
                                        qinb, catb, fwb, p1b, p2b);
    dim3 hg2(64, 2), hg4(64, 4);
    head_gemm_kernel<<<hg2, 256, 0, stream>>>(catb, fwb, fusion_b, qinb, nullptr, 128, 256, 0);
    head_gemm_kernel<<<hg4, 256, 0, stream>>>(qinb, p1b, proj1_b, q1b, nullptr, 0, 256, 1);
    head_gemm_kernel<<<hg2, 256, 0, stream>>>(q1b, p2b, proj2_b, nullptr, query, 0, 128, 0);
}

// Round 13
// 192.638 us; speedup vs baseline: 1.4455x; 1.0437x over previous
//
#include <hip/hip_runtime.h>

#define NN 50000
#define NE 800000
#define DIM 128
#define NB 1024
#define CTXL 50
#define BN_EPS 1e-5f
#define STRIPS 3125     // NN/16
#define GEMM_BLOCKS 512 // 2 blocks/CU at 64KB LDS
#define NBK 49          // buckets of 1024 rows
#define BCAP 20000      // bucket capacity
#define ABLK 1024       // edges per passA block
#define NAB 782         // ceil(NE/ABLK)

// ---------------- ws layout (float offsets) ----------------
static const size_t OFF_Z    = 0;          // zb bf16 [NN][128] 3.2M f; head aliases here after resid2
static const size_t OFF_AH   = 6400000;    // Ah bf16 [NN][128]; acnt/aofs/btot alias during CSR build
static const size_t OFF_HBF  = 9600000;    // hbf bf16 [NN][128]
static const size_t OFF_EDG  = 12800000;   // (col,norm) pairs [NE][2]
static const size_t OFF_RS   = 14400000;   // row_start [NN+1] int
static const size_t OFF_SCSH = 14550400;   // scale/shift [256] f
static const size_t OFF_WH   = 14550656;   // Wh bf16 [2][128][128]
static const size_t OFF_WL   = 14567040;   // Wl bf16 [2][128][128]
// aliases in dead regions:
static const size_t OFF_BKT  = OFF_Z + 3200000;  // bkt u64 [49][20000] (CSR build); later P2
static const size_t OFF_P2   = OFF_Z + 3200000;  // BN partials [512][256] f (gemm phase)
static const size_t OFF_ACNT = OFF_AH;           // cnt int [49][784]
static const size_t OFF_AOFS = OFF_AH + 40000;   // ofs int [49][784]
static const size_t OFF_BTOT = OFF_AH + 80000;   // btot int [49]
static const size_t OFF_QIN  = OFF_Z;            // qin bf16 [1024][256] (head phase)
static const size_t OFF_CAT  = OFF_Z + 131072;
static const size_t OFF_Q1   = OFF_Z + 262144;
static const size_t OFF_FWB  = OFF_Z + 393216;
static const size_t OFF_P1B  = OFF_Z + 409600;
static const size_t OFF_P2B  = OFF_Z + 442368;   // end 458752

typedef __attribute__((ext_vector_type(8))) short s16x8;
typedef __attribute__((ext_vector_type(4))) float fx4;

__device__ __forceinline__ unsigned short f2bf(float f) {
    unsigned u = __float_as_uint(f);
    unsigned r = u + 0x7FFFu + ((u >> 16) & 1u);
    return (unsigned short)(r >> 16);
}
__device__ __forceinline__ float bf2f(unsigned short b) {
    return __uint_as_float((unsigned)b << 16);
}

// ---------------- CSR pass A count + W split + h cast (fused) ----------------
__global__ __launch_bounds__(256) void csr_prep_kernel(const int* __restrict__ row,
                                                       const float* __restrict__ W,
                                                       const float* __restrict__ fg,
                                                       int* __restrict__ cnt,
                                                       unsigned short* __restrict__ Wh,
                                                       unsigned short* __restrict__ Wl,
                                                       unsigned short* __restrict__ hbf) {
    int i = blockIdx.x * 256 + threadIdx.x;
    if (i < 2 * DIM * DIM) {
        float v = W[i];
        unsigned short h = f2bf(v);
        Wh[i] = h;
        Wl[i] = f2bf(v - bf2f(h));
    }
    if (i < NN * DIM / 4) {
        float4 v = reinterpret_cast<const float4*>(fg)[i];
        reinterpret_cast<ushort4*>(hbf)[i] =
            make_ushort4(f2bf(v.x), f2bf(v.y), f2bf(v.z), f2bf(v.w));
    }
    if (blockIdx.x < NAB) {
        __shared__ int c[NBK];
        int t = threadIdx.x;
        if (t < NBK) c[t] = 0;
        __syncthreads();
        int base = blockIdx.x * ABLK;
        #pragma unroll
        for (int k = 0; k < 4; k++) {
            int e = base + k * 256 + t;
            if (e < NE) atomicAdd(&c[row[e] >> 10], 1);
        }
        __syncthreads();
        if (t < NBK) cnt[t * 784 + blockIdx.x] = c[t];
    }
}

__global__ __launch_bounds__(1024) void binA_scan(const int* __restrict__ cnt,
                                                  int* __restrict__ ofs,
                                                  int* __restrict__ btot) {
    __shared__ int lds[1024];
    int b = blockIdx.x, t = threadIdx.x;
    int v = (t < NAB) ? cnt[b * 784 + t] : 0;
    lds[t] = v;
    __syncthreads();
    for (int off = 1; off < 1024; off <<= 1) {
        int add = (t >= off) ? lds[t - off] : 0;
        __syncthreads();
        lds[t] += add;
        __syncthreads();
    }
    if (t < NAB) ofs[b * 784 + t] = lds[t] - v;   // exclusive
    if (t == NAB - 1) btot[b] = lds[t];
}

__global__ __launch_bounds__(256) void binA_scatter(const int* __restrict__ row,
                                                    const int* __restrict__ col,
                                                    const float* __restrict__ norm,
                                                    const int* __restrict__ ofs,
                                                    unsigned long long* __restrict__ bkt) {
    __shared__ int c[NBK], bofs[NBK], brsv[NBK];
    __shared__ unsigned long long stage[ABLK];
    __shared__ unsigned char stgb[ABLK];
    int t = threadIdx.x;
    if (t < NBK) c[t] = 0;
    __syncthreads();
    int base = blockIdx.x * ABLK;
    int my_b[4], my_i[4];
    unsigned long long my_pk[4];
    #pragma unroll
    for (int k = 0; k < 4; k++) {
        int e = base + k * 256 + t;
        if (e < NE) {
            int r = row[e];
            int b = r >> 10;
            my_b[k] = b;
            my_i[k] = atomicAdd(&c[b], 1);
            my_pk[k] = ((unsigned long long)__float_as_uint(norm[e]) << 32)
                     | ((unsigned long long)(unsigned)col[e] << 10)
                     | (unsigned)(r & 1023);
        } else my_b[k] = -1;
    }
    __syncthreads();
    if (t == 0) {
        int s = 0;
        for (int b = 0; b < NBK; b++) { bofs[b] = s; s += c[b]; }
    }
    if (t < NBK) brsv[t] = ofs[t * 784 + blockIdx.x];
    __syncthreads();
    #pragma unroll
    for (int k = 0; k < 4; k++) {
        if (my_b[k] >= 0) {
            int j = bofs[my_b[k]] + my_i[k];
            stage[j] = my_pk[k];
            stgb[j] = (unsigned char)my_b[k];
        }
    }
    __syncthreads();
    int tot = min(NE - base, ABLK);
    for (int j = t; j < tot; j += 256) {
        int b = stgb[j];
        int dst = brsv[b] + (j - bofs[b]);
        if (dst < BCAP) bkt[(size_t)b * BCAP + dst] = stage[j];
    }
}

// pass B fused: per-bucket histogram + prefix -> row_start, then scatter (bkt L2-hot 2nd pass)
__global__ __launch_bounds__(1024) void binB_kernel(const unsigned long long* __restrict__ bkt,
                                                    const int* __restrict__ btot,
                                                    int* __restrict__ row_start,
                                                    unsigned long long* __restrict__ edge_out) {
    __shared__ int c[1024];
    __shared__ int rs[1024];
    __shared__ int gofs_s;
    int b = blockIdx.x, t = threadIdx.x;
    c[t] = 0;
    if (t < 64) {
        int v = (t < b) ? btot[t] : 0;
        #pragma unroll
        for (int off = 32; off; off >>= 1) v += __shfl_down(v, off);
        if (t == 0) gofs_s = v;
    }
    __syncthreads();
    int n = btot[b];
    size_t bb = (size_t)b * BCAP;
    for (int i = t; i < n; i += 1024)
        atomicAdd(&c[(int)(bkt[bb + i] & 1023u)], 1);
    __syncthreads();
    int myc = c[t];
    for (int off = 1; off < 1024; off <<= 1) {
        int add = (t >= off) ? c[t - off] : 0;
        __syncthreads();
        c[t] += add;
        __syncthreads();
    }
    int excl = gofs_s + c[t] - myc;
    rs[t] = excl;
    int r = (b << 10) + t;
    if (r <= NN) row_start[r] = excl;   // r==NN (b=48,t=848) lands excl==NE
    __syncthreads();
    c[t] = 0;
    __syncthreads();
    for (int i = t; i < n; i += 1024) {
        unsigned long long pk = bkt[bb + i];
        int lr = (int)(pk & 1023u);
        unsigned colv = (unsigned)((pk >> 10) & 0xFFFFu);
        unsigned nrm = (unsigned)(pk >> 32);
        int k = atomicAdd(&c[lr], 1);
        edge_out[rs[lr] + k] = ((unsigned long long)nrm << 32) | colv;
    }
}

// ---------------- aggregation: one wave per row, half-wave edge split, ushort4 loads ----------------
__global__ __launch_bounds__(256) void agg_bf_kernel(const unsigned short* __restrict__ hbf,
                                                     const int* __restrict__ row_start,
                                                     const float* __restrict__ edge_s,
                                                     unsigned short* __restrict__ Ah) {
    int gw = (blockIdx.x * 256 + threadIdx.x) >> 6;
    int lane = threadIdx.x & 63;
    int half = lane >> 5;
    int c4 = (lane & 31) * 4;
    if (gw >= NN) return;
    int s = row_start[gw];
    int e = row_start[gw + 1];
    const int2* ep = (const int2*)edge_s;
    float a0 = 0.f, a1 = 0.f, a2 = 0.f, a3 = 0.f;
    int j = s + half;
    for (; j + 6 < e; j += 8) {
        int2 p0 = ep[j], p1 = ep[j + 2], p2 = ep[j + 4], p3 = ep[j + 6];
        ushort4 v0 = *(const ushort4*)(hbf + (size_t)p0.x * DIM + c4);
        ushort4 v1 = *(const ushort4*)(hbf + (size_t)p1.x * DIM + c4);
        ushort4 v2 = *(const ushort4*)(hbf + (size_t)p2.x * DIM + c4);
        ushort4 v3 = *(const ushort4*)(hbf + (size_t)p3.x * DIM + c4);
        float w0 = __int_as_float(p0.y), w1 = __int_as_float(p1.y);
        float w2 = __int_as_float(p2.y), w3 = __int_as_float(p3.y);
        a0 = fmaf(w0, bf2f(v0.x), a0); a1 = fmaf(w0, bf2f(v0.y), a1);
        a2 = fmaf(w0, bf2f(v0.z), a2); a3 = fmaf(w0, bf2f(v0.w), a3);
        a0 = fmaf(w1, bf2f(v1.x), a0); a1 = fmaf(w1, bf2f(v1.y), a1);
        a2 = fmaf(w1, bf2f(v1.z), a2); a3 = fmaf(w1, bf2f(v1.w), a3);
        a0 = fmaf(w2, bf2f(v2.x), a0); a1 = fmaf(w2, bf2f(v2.y), a1);
        a2 = fmaf(w2, bf2f(v2.z), a2); a3 = fmaf(w2, bf2f(v2.w), a3);
        a0 = fmaf(w3, bf2f(v3.x), a0); a1 = fmaf(w3, bf2f(v3.y), a1);
        a2 = fmaf(w3, bf2f(v3.z), a2); a3 = fmaf(w3, bf2f(v3.w), a3);
    }
    for (; j < e; j += 2) {
        int2 p = ep[j];
        ushort4 v = *(const ushort4*)(hbf + (size_t)p.x * DIM + c4);
        float w = __int_as_float(p.y);
        a0 = fmaf(w, bf2f(v.x), a0); a1 = fmaf(w, bf2f(v.y), a1);
        a2 = fmaf(w, bf2f(v.z), a2); a3 = fmaf(w, bf2f(v.w), a3);
    }
    a0 += __shfl_xor(a0, 32); a1 += __shfl_xor(a1, 32);
    a2 += __shfl_xor(a2, 32); a3 += __shfl_xor(a3, 32);
    if (half == 0) {
        *(ushort4*)(Ah + (size_t)gw * DIM + c4) =
            make_ushort4(f2bf(a0), f2bf(a1), f2bf(a2), f2bf(a3));
    }
}

// ---------------- z = relu(agg @ W^T): full W (hi+lo) in 64KB LDS, 4 waves = 4 channel quarters ----
// A fragments loaded once per strip per block (wave redundancy hits L1); no grid.y.
__global__ __launch_bounds__(256) void gemm_mfma_kernel(const unsigned short* __restrict__ Ah,
                                                        const unsigned short* __restrict__ Wh,
                                                        const unsigned short* __restrict__ Wl,
                                                        unsigned short* __restrict__ zb,
                                                        float* __restrict__ P2) {
    __shared__ __align__(16) short Wlds[2][128][128];  // 64 KB exactly
    int tid = threadIdx.x;
    int lane = tid & 63;
    int w = tid >> 6;        // wave id == channel quarter
    int r16 = lane & 15;
    int kg = lane >> 4;

    #pragma unroll
    for (int ff = 0; ff < 16; ff++) {
        int f = ff * 256 + tid;    // 4096 16B-chunks
        int plane = f >> 11;
        int c = (f >> 4) & 127;
        int ck = f & 15;
        const unsigned short* srcp = (plane ? Wl : Wh) + (size_t)c * DIM + ck * 8;
        *(s16x8*)&Wlds[plane][c][(ck ^ (c & 7)) * 8] = *(const s16x8*)srcp;
    }
    __syncthreads();

    float bsum[2][4] = {{0.f}}, bsq[2][4] = {{0.f}};

    for (int strip = blockIdx.x; strip < STRIPS; strip += GEMM_BLOCKS) {
        size_t abase = (size_t)(strip * 16 + r16) * DIM + kg * 8;
        s16x8 b[4];
        #pragma unroll
        for (int ks = 0; ks < 4; ks++) b[ks] = *(const s16x8*)(Ah + abase + ks * 32);

        fx4 acc[2];
        acc[0] = (fx4){0.f, 0.f, 0.f, 0.f};
        acc[1] = (fx4){0.f, 0.f, 0.f, 0.f};
        #pragma unroll
        for (int ks = 0; ks < 4; ks++) {
            #pragma unroll
            for (int ct = 0; ct < 2; ct++) {
                int wrow = w * 32 + ct * 16 + r16;       // wrow&7 == r16&7
                int wch = ((ks * 4 + kg) ^ (r16 & 7)) * 8;
                s16x8 wh8 = *(const s16x8*)&Wlds[0][wrow][wch];
                s16x8 wl8 = *(const s16x8*)&Wlds[1][wrow][wch];
                acc[ct] = __builtin_amdgcn_mfma_f32_16x16x32_bf16(wh8, b[ks], acc[ct], 0, 0, 0);
                acc[ct] = __builtin_amdgcn_mfma_f32_16x16x32_bf16(wl8, b[ks], acc[ct], 0, 0, 0);
            }
        }
        size_t zrow = (size_t)(strip * 16 + r16) * DIM + w * 32 + kg * 4;
        #pragma unroll
        for (int ct = 0; ct < 2; ct++) {
            float x0 = fmaxf(acc[ct][0], 0.f);
            float x1 = fmaxf(acc[ct][1], 0.f);
            float x2 = fmaxf(acc[ct][2], 0.f);
            float x3 = fmaxf(acc[ct][3], 0.f);
            bsum[ct][0] += x0; bsq[ct][0] += x0 * x0;
            bsum[ct][1] += x1; bsq[ct][1] += x1 * x1;
            bsum[ct][2] += x2; bsq[ct][2] += x2 * x2;
            bsum[ct][3] += x3; bsq[ct][3] += x3 * x3;
            *(ushort4*)(zb + zrow + ct * 16) = make_ushort4(f2bf(x0), f2bf(x1), f2bf(x2), f2bf(x3));
        }
    }

    // per-wave reduce over r16 lanes; each wave owns distinct channels -> write P2 directly
    #pragma unroll
    for (int ct = 0; ct < 2; ct++) {
        #pragma unroll
        for (int jj = 0; jj < 4; jj++) {
            float s = bsum[ct][jj], q = bsq[ct][jj];
            #pragma unroll
            for (int off = 1; off <= 8; off <<= 1) {
                s += __shfl_xor(s, off);
                q += __shfl_xor(q, off);
            }
            if (r16 == 0) {
                int ch = w * 32 + ct * 16 + kg * 4 + jj;
                P2[blockIdx.x * 256 + ch] = s;          // kind 0: sums at [0,128)
                P2[blockIdx.x * 256 + 128 + ch] = q;    // kind 1: sq at [128,256)
            }
        }
    }
}

// ---------------- BN finalize: 1024 threads, 4-way row split ----------------
__global__ __launch_bounds__(1024) void bn_finalize_kernel(const float* __restrict__ P2,
                                                           const float* __restrict__ gamma,
                                                           const float* __restrict__ beta,
                                                           float* __restrict__ scsh) {
    __shared__ float tot[4][256];
    int t = threadIdx.x & 255;
    int g = threadIdx.x >> 8;
    float a0 = 0.f, a1 = 0.f, a2 = 0.f, a3 = 0.f;
    int base = g * (GEMM_BLOCKS / 4);
    for (int bx = 0; bx < GEMM_BLOCKS / 4; bx += 4) {
        a0 += P2[(size_t)(base + bx + 0) * 256 + t];
        a1 += P2[(size_t)(base + bx + 1) * 256 + t];
        a2 += P2[(size_t)(base + bx + 2) * 256 + t];
        a3 += P2[(size_t)(base + bx + 3) * 256 + t];
    }
    tot[g][t] = (a0 + a1) + (a2 + a3);
    __syncthreads();
    if (threadIdx.x < 128) {
        int c = threadIdx.x;
        float sum = (tot[0][c] + tot[1][c]) + (tot[2][c] + tot[3][c]);
        float sq  = (tot[0][128 + c] + tot[1][128 + c]) + (tot[2][128 + c] + tot[3][128 + c]);
        float mu = sum * (1.f / (float)NN);
        float var = sq * (1.f / (float)NN) - mu * mu;
        float sc = gamma[c] / sqrtf(var + BN_EPS);
        scsh[c] = sc;
        scsh[128 + c] = beta[c] - mu * sc;
    }
}

// ---------------- h_out = h_in + zb*scale + shift (+ optional bf16 emit) ----------------
__global__ __launch_bounds__(256) void residual_kernel(const float* hin,
                                                       const unsigned short* zb,
                                                       const float* __restrict__ scsh,
                                                       float* hout,
                                                       unsigned short* hbf_out) {
    int i = blockIdx.x * 256 + threadIdx.x;
    if (i >= NN * DIM / 4) return;
    int c = (i * 4) & 127;
    ushort4 z4 = reinterpret_cast<const ushort4*>(zb)[i];
    float4 hv = reinterpret_cast<const float4*>(hin)[i];
    float4 sc = *reinterpret_cast<const float4*>(scsh + c);
    float4 sh = *reinterpret_cast<const float4*>(scsh + 128 + c);
    float4 o;
    o.x = hv.x + bf2f(z4.x) * sc.x + sh.x;
    o.y = hv.y + bf2f(z4.y) * sc.y + sh.y;
    o.z = hv.z + bf2f(z4.z) * sc.z + sh.z;
    o.w = hv.w + bf2f(z4.w) * sc.w + sh.w;
    reinterpret_cast<float4*>(hout)[i] = o;
    if (hbf_out) {
        ushort4 ob = make_ushort4(f2bf(o.x), f2bf(o.y), f2bf(o.z), f2bf(o.w));
        reinterpret_cast<ushort4*>(hbf_out)[i] = ob;
    }
}

// ---------------- pool: attention pooling + cat build + distributed head-weight cast ----------------
__global__ __launch_bounds__(256) void pool_kernel(const int* __restrict__ ctx_ids,
                                                   const int* __restrict__ miss_ids,
                                                   const int* __restrict__ vocab_to_fg,
                                                   const float* __restrict__ emb_table,
                                                   const float* __restrict__ graph,
                                                   const float* __restrict__ attn_w,
                                                   const float* __restrict__ attn_b,
                                                   const float* __restrict__ fusion_w,
                                                   const float* __restrict__ proj1_w,
                                                   const float* __restrict__ proj2_w,
                                                   unsigned short* __restrict__ qinb,
                                                   unsigned short* __restrict__ catb,
                                                   unsigned short* __restrict__ fwb,
                                                   unsigned short* __restrict__ p1b,
                                                   unsigned short* __restrict__ p2b) {
    int b = blockIdx.x;
    int tid = threadIdx.x;
    __shared__ float ctx[CTXL][129];
    __shared__ float aw[128];
    __shared__ float lg[64];

    if (tid < 128) {
        int i = b * 128 + tid;
        if (i < 32768) fwb[i] = f2bf(fusion_w[i]);
        else if (i < 98304) p1b[i - 32768] = f2bf(proj1_w[i - 32768]);
        else p2b[i - 98304] = f2bf(proj2_w[i - 98304]);
    }

    if (tid < 128) aw[tid] = attn_w[tid];
    for (int f = tid; f < CTXL * 32; f += 256) {
        int t = f >> 5, d4 = (f & 31) * 4;
        int vid = ctx_ids[b * CTXL + t];
        float4 v = *(const float4*)(emb_table + (size_t)vid * DIM + d4);
        ctx[t][d4 + 0] = v.x; ctx[t][d4 + 1] = v.y;
        ctx[t][d4 + 2] = v.z; ctx[t][d4 + 3] = v.w;
    }
    __syncthreads();

    if (tid < CTXL) {
        float s = 0.f;
        for (int k = 0; k < 128; k++) s += ctx[tid][k] * aw[k];
        lg[tid] = s + attn_b[0];
    }
    __syncthreads();

    if (tid < 64) {
        float v = (tid < CTXL) ? lg[tid] : -INFINITY;
        float m = v;
        for (int off = 32; off; off >>= 1) m = fmaxf(m, __shfl_xor(m, off));
        float e = (tid < CTXL) ? expf(v - m) : 0.f;
        float s = e;
        for (int off = 32; off; off >>= 1) s += __shfl_xor(s, off);
        if (tid < CTXL) lg[tid] = e / s;
    }
    __syncthreads();

    int mid = miss_ids[b];
    if (tid < 128) {
        float s = 0.f;
        for (int t = 0; t < CTXL; t++) s += lg[t] * ctx[t][tid];
        qinb[(size_t)b * 256 + tid] = f2bf(s);
        catb[(size_t)b * 256 + tid] = f2bf(emb_table[(size_t)mid * DIM + tid]);
    } else {
        int d = tid - 128;
        int fg = vocab_to_fg[mid];
        float gp = (fg >= 0) ? graph[(size_t)fg * DIM + d] : 0.f;
        catb[(size_t)b * 256 + tid] = f2bf(gp);
    }
}

// ---------------- head GEMM ----------------
__global__ __launch_bounds__(256) void head_gemm_kernel(const unsigned short* __restrict__ A,
                                                        const unsigned short* __restrict__ W,
                                                        const float* __restrict__ bias,
                                                        unsigned short* __restrict__ outb,
                                                        float* __restrict__ outf,
                                                        int ocol, int ostride, int relu) {
    __shared__ __align__(16) short Wlds[64][256];  // 32 KB
    int tid = threadIdx.x;
    int lane = tid & 63;
    int r16 = lane & 15;
    int kg = lane >> 4;
    int cgb = blockIdx.y * 64;

    #pragma unroll
    for (int ff = 0; ff < 8; ff++) {
        int f = ff * 256 + tid;
        int c = f >> 5;
        int ck = f & 31;
        s16x8 v = *(const s16x8*)(W + (size_t)(cgb + c) * 256 + ck * 8);
        *(s16x8*)&Wlds[c][(ck ^ (c & 7)) * 8] = v;
    }
    __syncthreads();

    int w = tid >> 6;
    int row = blockIdx.x * 16 + r16;

    size_t abase = (size_t)row * 256 + kg * 8;
    s16x8 bfrag[8];
    #pragma unroll
    for (int ks = 0; ks < 8; ks++) bfrag[ks] = *(const s16x8*)(A + abase + ks * 32);

    fx4 acc = (fx4){0.f, 0.f, 0.f, 0.f};
    int wrow = w * 16 + r16;
    #pragma unroll
    for (int ks = 0; ks < 8; ks++) {
        int wch = (((ks * 4 + kg) ^ (r16 & 7))) * 8;
        s16x8 w8 = *(const s16x8*)&Wlds[wrow][wch];
        acc = __builtin_amdgcn_mfma_f32_16x16x32_bf16(w8, bfrag[ks], acc, 0, 0, 0);
    }

    int cbase = cgb + w * 16 + kg * 4;
    float4 o;
    o.x = acc[0] + bias[cbase + 0];
    o.y = acc[1] + bias[cbase + 1];
    o.z = acc[2] + bias[cbase + 2];
    o.w = acc[3] + bias[cbase + 3];
    if (relu) {
        o.x = fmaxf(o.x, 0.f); o.y = fmaxf(o.y, 0.f);
        o.z = fmaxf(o.z, 0.f); o.w = fmaxf(o.w, 0.f);
    }
    size_t op = (size_t)row * ostride + ocol + cbase;
    if (outb) {
        *(ushort4*)(outb + op) = make_ushort4(f2bf(o.x), f2bf(o.y), f2bf(o.z), f2bf(o.w));
    } else {
        *(float4*)(outf + op) = o;
    }
}

extern "C" void kernel_launch(void* const* d_in, const int* in_sizes, int n_in,
                              void* d_out, int out_size, void* d_ws, size_t ws_size,
                              hipStream_t stream) {
    const int*   edge_index = (const int*)d_in[0];
    const float* norm       = (const float*)d_in[1];
    const int*   ctx_ids    = (const int*)d_in[2];
    const int*   miss_ids   = (const int*)d_in[3];
    const int*   vocab_to_fg= (const int*)d_in[4];
    const float* emb_table  = (const float*)d_in[5];
    const float* fg_emb     = (const float*)d_in[6];
    const float* gc_w       = (const float*)d_in[7];
    const float* bn_gamma   = (const float*)d_in[8];
    const float* bn_beta    = (const float*)d_in[9];
    const float* attn_w     = (const float*)d_in[10];
    const float* attn_b     = (const float*)d_in[11];
    const float* fusion_w   = (const float*)d_in[12];
    const float* fusion_b   = (const float*)d_in[13];
    const float* proj1_w    = (const float*)d_in[14];
    const float* proj1_b    = (const float*)d_in[15];
    const float* proj2_w    = (const float*)d_in[16];
    const float* proj2_b    = (const float*)d_in[17];

    const int* row = edge_index;
    const int* col = edge_index + NE;

    float* ws = (float*)d_ws;
    unsigned short* zb     = (unsigned short*)(ws + OFF_Z);
    unsigned short* Ah     = (unsigned short*)(ws + OFF_AH);
    unsigned short* hbf    = (unsigned short*)(ws + OFF_HBF);
    float*          edge_s = ws + OFF_EDG;
    int*   row_start = (int*)(ws + OFF_RS);
    float* scsh      = ws + OFF_SCSH;
    unsigned short* Wh = (unsigned short*)(ws + OFF_WH);
    unsigned short* Wl = (unsigned short*)(ws + OFF_WL);
    float* P2        = ws + OFF_P2;
    unsigned long long* bkt = (unsigned long long*)(ws + OFF_BKT);
    int*   acnt      = (int*)(ws + OFF_ACNT);
    int*   aofs      = (int*)(ws + OFF_AOFS);
    int*   btot      = (int*)(ws + OFF_BTOT);
    unsigned short* qinb = (unsigned short*)(ws + OFF_QIN);
    unsigned short* catb = (unsigned short*)(ws + OFF_CAT);
    unsigned short* q1b  = (unsigned short*)(ws + OFF_Q1);
    unsigned short* fwb  = (unsigned short*)(ws + OFF_FWB);
    unsigned short* p1b  = (unsigned short*)(ws + OFF_P1B);
    unsigned short* p2b  = (unsigned short*)(ws + OFF_P2B);

    float* query = (float*)d_out;
    float* G     = (float*)d_out + (size_t)NB * DIM;  // graph_embs, doubles as h

    // ---- CSR build (bucketed counting sort, zero global atomics) + prep fused ----
    csr_prep_kernel<<<6250, 256, 0, stream>>>(row, gc_w, fg_emb, acnt, Wh, Wl, hbf);
    binA_scan<<<NBK, 1024, 0, stream>>>(acnt, aofs, btot);
    binA_scatter<<<NAB, 256, 0, stream>>>(row, col, norm, aofs, bkt);
    binB_kernel<<<NBK, 1024, 0, stream>>>(bkt, btot, row_start, (unsigned long long*)edge_s);

    const int AGG_B = NN / 4;                 // 12500 blocks, one wave per row
    const int RES_B = (NN * DIM / 4) / 256;   // 6250

    // ---- layer 1 ----
    agg_bf_kernel<<<AGG_B, 256, 0, stream>>>(hbf, row_start, edge_s, Ah);
    gemm_mfma_kernel<<<GEMM_BLOCKS, 256, 0, stream>>>(Ah, Wh, Wl, zb, P2);
    bn_finalize_kernel<<<1, 1024, 0, stream>>>(P2, bn_gamma, bn_beta, scsh);
    residual_kernel<<<RES_B, 256, 0, stream>>>(fg_emb, zb, scsh, G, hbf);

    // ---- layer 2 ----
    agg_bf_kernel<<<AGG_B, 256, 0, stream>>>(hbf, row_start, edge_s, Ah);
    gemm_mfma_kernel<<<GEMM_BLOCKS, 256, 0, stream>>>(Ah, Wh + DIM * DIM, Wl + DIM * DIM, zb, P2);
    bn_finalize_kernel<<<1, 1024, 0, stream>>>(P2, bn_gamma + 128, bn_beta + 128, scsh);
    residual_kernel<<<RES_B, 256, 0, stream>>>(G, zb, scsh, G, nullptr);

    // ---- batch head: zb region now dead -> head aliases live there ----
    pool_kernel<<<NB, 256, 0, stream>>>(ctx_ids, miss_ids, vocab_to_fg, emb_table, G,
                                        attn_w, attn_b, fusion_w, proj1_w, proj2_w,
                                        qinb, catb, fwb, p1b, p2b);
    dim3 hg2(64, 2), hg4(64, 4);
    head_gemm_kernel<<<hg2, 256, 0, stream>>>(catb, fwb, fusion_b, qinb, nullptr, 128, 256, 0);
    head_gemm_kernel<<<hg4, 256, 0, stream>>>(qinb, p1b, proj1_b, q1b, nullptr, 0, 256, 1);
    head_gemm_kernel<<<hg2, 256, 0, stream>>>(q1b, p2b, proj2_b, nullptr, query, 0, 128, 0);
}